// Round 20
// baseline (142.091 us; speedup 1.0000x reference)
//
#include <hip/hip_runtime.h>
#include <cmath>

#define D_MODEL 1024
#define QLEN    1024
#define NHEAD   16
#define DHEAD   64
#define BSZ     4

typedef __bf16 bf16x8 __attribute__((ext_vector_type(8)));
typedef float  f32x4  __attribute__((ext_vector_type(4)));

static __device__ __forceinline__ __bf16 f2bf(float x) { return (__bf16)x; }

#define MFMA16(a, b, c) __builtin_amdgcn_mfma_f32_16x16x32_bf16((a), (b), (c), 0, 0, 0)

// async global->LDS, 16B per lane. dest = wave-uniform base + lane*16B.
typedef const __attribute__((address_space(1))) void* gp1_t;
typedef __attribute__((address_space(3))) void* lp3_t;
static __device__ __forceinline__ void gll16(const __bf16* g, const __bf16* l)
{
    __builtin_amdgcn_global_load_lds((gp1_t)g, (lp3_t)(__bf16*)l, 16, 0, 0);
}

static __device__ __forceinline__ int mod6(int c)
{
    if (c >= 24) c -= 24;
    if (c >= 12) c -= 12;
    if (c >= 6)  c -= 6;
    return c;
}

// ---------------------------------------------------------------------------
// MERGED prep: weight converts (bid<2560) + z/pos transpose (2560<=bid<3840).
// ---------------------------------------------------------------------------
__global__ __launch_bounds__(256)
void prep_kernel(const float* __restrict__ qkv_w, const float* __restrict__ r_w,
                 const float* __restrict__ o_w, const float* __restrict__ z,
                 const float* __restrict__ pos, __bf16* __restrict__ qw_bf,
                 __bf16* __restrict__ rw_bf, __bf16* __restrict__ ow_bf,
                 __bf16* __restrict__ zT, __bf16* __restrict__ posT)
{
    const int bid = blockIdx.x;
    if (bid < 2560) {
        const int i = bid * 256 + threadIdx.x;
        const float* s; __bf16* d; int j;
        if (i < 393216)      { s = qkv_w; d = qw_bf; j = i; }
        else if (i < 524288) { s = r_w;   d = rw_bf; j = i - 393216; }
        else                 { s = o_w;   d = ow_bf; j = i - 524288; }
        const float4 a = *(const float4*)(s + (size_t)j * 8);
        const float4 b = *(const float4*)(s + (size_t)j * 8 + 4);
        bf16x8 o;
        o[0] = f2bf(a.x); o[1] = f2bf(a.y); o[2] = f2bf(a.z); o[3] = f2bf(a.w);
        o[4] = f2bf(b.x); o[5] = f2bf(b.y); o[6] = f2bf(b.z); o[7] = f2bf(b.w);
        *(bf16x8*)(d + (size_t)j * 8) = o;
        return;
    }
    // transpose path
    const int lo   = bid - 2560;          // 0..1279
    const int slab = lo >> 8;             // 0..4
    const int rem  = lo & 255;
    const int c0   = (rem >> 4) * 64;
    const int l0   = (rem & 15) * 64;
    const float* src = (slab < 4) ? z + (size_t)slab * 1048576 : pos;
    __bf16*      dst = (slab < 4) ? zT + (size_t)slab * 1048576 : posT;

    __shared__ float tile[64][68];
    const int t = threadIdx.x;
    {
        const int c = t >> 4, l4 = (t & 15) * 4;
#pragma unroll
        for (int r = 0; r < 4; ++r) {
            const int cc = c + r * 16;
            const float4 v = *(const float4*)(src + (size_t)(c0 + cc) * 1024 + l0 + l4);
            tile[cc][l4 + 0] = v.x; tile[cc][l4 + 1] = v.y;
            tile[cc][l4 + 2] = v.z; tile[cc][l4 + 3] = v.w;
        }
    }
    __syncthreads();
    {
        const int l = t >> 2, cb = (t & 3) * 16;
#pragma unroll
        for (int h = 0; h < 2; ++h) {
            bf16x8 o;
#pragma unroll
            for (int e = 0; e < 8; ++e) o[e] = f2bf(tile[cb + h * 8 + e][l]);
            *(bf16x8*)(dst + (size_t)(l0 + l) * 1024 + c0 + cb + h * 8) = o;
        }
    }
}

// ---------------------------------------------------------------------------
// MERGED pre-attention GEMM: QKV-T + V + rk in ONE launch, 128x64 tiles,
// 48KB LDS -> 3 blocks/CU, 1664 blocks.
//   bid [0,1024):    mode 1  whqkT[l][c] transposed out (+u), M=2048
//   bid [1024,1536): mode 0  wh_v natural bf16 out (+u), M=1024 (V section)
//   bid [1536,1664): mode 2  rkT[r][c] transposed out, M=1024, batch 1
// XCD-pinned via bid&7 = n-tile low bits.
// ---------------------------------------------------------------------------
__global__ __launch_bounds__(256)
void gemm_pre_kernel(const __bf16* __restrict__ qw, const __bf16* __restrict__ zT,
                     const float* __restrict__ u, __bf16* __restrict__ whqkT,
                     __bf16* __restrict__ wh_v, const __bf16* __restrict__ rw,
                     const __bf16* __restrict__ posT, __bf16* __restrict__ rkT)
{
    const int bid = blockIdx.x;
    int mode, nt2, mt, b;
    const __bf16 *A, *Bb;
    if (bid < 1024)      { mode = 1; nt2 = bid & 15; const int ix = bid >> 4; mt = ix & 15; b = ix >> 4;
                           A = qw;                       Bb = zT + (size_t)b * 1048576; }
    else if (bid < 1536) { mode = 0; const int lo = bid - 1024; nt2 = lo & 15; const int ix = lo >> 4; mt = ix & 7; b = ix >> 3;
                           A = qw + (size_t)2048 * 1024; Bb = zT + (size_t)b * 1048576; }
    else                 { mode = 2; const int lo = bid - 1536; nt2 = lo & 15; mt = lo >> 4; b = 0;
                           A = rw;                       Bb = posT; }
    const int m0 = mt * 128;
    const int n0 = nt2 * 64;
    const int K = 1024;

    __shared__ __align__(16) __bf16 As_[2][128 * 64];   // 16KB x2
    __shared__ __align__(16) __bf16 Bs_[2][64 * 64];    // 8KB x2

    const int t  = threadIdx.x;
    const int w  = t >> 6, l = t & 63;
    const int lr = l & 15, lg = l >> 4;
    const int wr = w >> 1, wc = w & 1;

    f32x4 acc[4][2];
#pragma unroll
    for (int mi = 0; mi < 4; ++mi)
#pragma unroll
        for (int ni = 0; ni < 2; ++ni) acc[mi][ni] = (f32x4){0.f, 0.f, 0.f, 0.f};

#define GSTA(bufsel, kk0) do {                                                 \
    _Pragma("unroll")                                                          \
    for (int cc = 0; cc < 4; ++cc) {                                           \
        const int ch  = w * 4 + cc;                                            \
        const int row = ch * 8 + (l >> 3);                                     \
        const int c16 = (l & 7) ^ (row & 7);                                   \
        gll16(A + (size_t)(m0 + row) * K + (kk0) + c16 * 8,                    \
              As_[bufsel] + ch * 512);                                         \
    }                                                                          \
    _Pragma("unroll")                                                          \
    for (int cc = 0; cc < 2; ++cc) {                                           \
        const int ch  = w * 2 + cc;                                            \
        const int row = ch * 8 + (l >> 3);                                     \
        const int c16 = (l & 7) ^ (row & 7);                                   \
        gll16(Bb + (size_t)(n0 + row) * K + (kk0) + c16 * 8,                   \
              Bs_[bufsel] + ch * 512);                                         \
    }                                                                          \
} while (0)

    GSTA(0, 0);
    __syncthreads();

    int buf = 0;
    for (int k0 = 0; k0 < K; k0 += 64) {
        if (k0 + 64 < K) GSTA(buf ^ 1, k0 + 64);

        const __bf16* As = As_[buf];
        const __bf16* Bs = Bs_[buf];
        __builtin_amdgcn_s_setprio(1);
#pragma unroll
        for (int kk = 0; kk < 2; ++kk) {
            bf16x8 af[4], bfr[2];
#pragma unroll
            for (int mi = 0; mi < 4; ++mi) {
                const int row = wr * 64 + mi * 16 + lr;
                af[mi] = *(const bf16x8*)(As + row * 64 + (((kk * 4 + lg) ^ (row & 7)) << 3));
            }
#pragma unroll
            for (int ni = 0; ni < 2; ++ni) {
                const int row = wc * 32 + ni * 16 + lr;
                bfr[ni] = *(const bf16x8*)(Bs + row * 64 + (((kk * 4 + lg) ^ (row & 7)) << 3));
            }
#pragma unroll
            for (int mi = 0; mi < 4; ++mi)
#pragma unroll
                for (int ni = 0; ni < 2; ++ni)
                    acc[mi][ni] = MFMA16(af[mi], bfr[ni], acc[mi][ni]);
        }
        __builtin_amdgcn_s_setprio(0);
        __syncthreads();
        buf ^= 1;
    }
#undef GSTA

    if (mode == 0) {
        // natural bf16 out, +u (V section: global row = 2048 + m)
        __bf16* Cb = wh_v + (size_t)b * 1048576;
#pragma unroll
        for (int mi = 0; mi < 4; ++mi)
#pragma unroll
        for (int q = 0; q < 4; ++q) {
            const int m = m0 + wr * 64 + mi * 16 + lg * 4 + q;
            const float* up = u + (size_t)b * 3145728 + (size_t)(2048 + m) * 1024;
#pragma unroll
            for (int ni = 0; ni < 2; ++ni) {
                const int n = n0 + wc * 32 + ni * 16 + lr;
                Cb[(size_t)m * 1024 + n] = f2bf(acc[mi][ni][q] + up[n]);
            }
        }
    } else {
        // transposed epilogue via LDS bounce: T[64 n][128 m] (stride 136)
        __syncthreads();
        __bf16 (*T)[136] = (__bf16(*)[136])As_;
#pragma unroll
        for (int mi = 0; mi < 4; ++mi)
#pragma unroll
        for (int ni = 0; ni < 2; ++ni)
#pragma unroll
        for (int q = 0; q < 4; ++q) {
            float v = acc[mi][ni][q];
            const int m = m0 + wr * 64 + mi * 16 + lg * 4 + q;
            const int n = n0 + wc * 32 + ni * 16 + lr;
            if (mode == 1) v += u[(size_t)b * 3145728 + (size_t)m * 1024 + n];
            T[wc * 32 + ni * 16 + lr][wr * 64 + mi * 16 + lg * 4 + q] = f2bf(v);
        }
        __syncthreads();
        const int Cw = (mode == 1) ? 2048 : 1024;
        __bf16* co = (mode == 1) ? whqkT + (size_t)b * 1024 * 2048 : rkT;
#pragma unroll
        for (int it2 = 0; it2 < 4; ++it2) {
            const int row = it2 * 16 + (t >> 4);
            const int col = (t & 15) * 8;
            *(bf16x8*)(co + (size_t)(n0 + row) * Cw + m0 + col) = *(const bf16x8*)&T[row][col];
        }
    }
}

// ---------------------------------------------------------------------------
// Out-projection GEMM: 128x64 tiles, 512 blocks, fp32 out, +o_b +z.
// Emits deterministic LN partial stats (slot mt*2+wr of 16).
// ---------------------------------------------------------------------------
__global__ __launch_bounds__(256)
void gemm_out_kernel(const __bf16* __restrict__ A, const __bf16* __restrict__ Bm,
                     const float* __restrict__ z, const float* __restrict__ bias,
                     float* __restrict__ Cout, float* __restrict__ lnS,
                     float* __restrict__ lnQ)
{
    const int nt2 = blockIdx.x & 15;       // 16 n-tiles of 64
    const int idx = blockIdx.x >> 4;
    const int mt  = idx & 7;
    const int b   = idx >> 3;
    const int m0  = mt * 128;
    const int n0  = nt2 * 64;
    const int K = 1024, N = 1024;
    const __bf16* Bb = Bm + (size_t)b * 1048576;

    __shared__ __align__(16) __bf16 As_[2][128 * 64];   // 16KB x2
    __shared__ __align__(16) __bf16 Bs_[2][64 * 64];    // 8KB x2

    const int t  = threadIdx.x;
    const int w  = t >> 6, l = t & 63;
    const int lr = l & 15, lg = l >> 4;
    const int wr = w >> 1, wc = w & 1;

    f32x4 acc[4][2];
#pragma unroll
    for (int mi = 0; mi < 4; ++mi)
#pragma unroll
        for (int ni = 0; ni < 2; ++ni) acc[mi][ni] = (f32x4){0.f, 0.f, 0.f, 0.f};

#define GSTA(bufsel, kk0) do {                                                 \
    _Pragma("unroll")                                                          \
    for (int cc = 0; cc < 4; ++cc) {                                           \
        const int ch  = w * 4 + cc;                                            \
        const int row = ch * 8 + (l >> 3);                                     \
        const int c16 = (l & 7) ^ (row & 7);                                   \
        gll16(A + (size_t)(m0 + row) * K + (kk0) + c16 * 8,                    \
              As_[bufsel] + ch * 512);                                         \
    }                                                                          \
    _Pragma("unroll")                                                          \
    for (int cc = 0; cc < 2; ++cc) {                                           \
        const int ch  = w * 2 + cc;                                            \
        const int row = ch * 8 + (l >> 3);                                     \
        const int c16 = (l & 7) ^ (row & 7);                                   \
        gll16(Bb + (size_t)(n0 + row) * K + (kk0) + c16 * 8,                   \
              Bs_[bufsel] + ch * 512);                                         \
    }                                                                          \
} while (0)

    GSTA(0, 0);
    __syncthreads();

    int buf = 0;
    for (int k0 = 0; k0 < K; k0 += 64) {
        if (k0 + 64 < K) GSTA(buf ^ 1, k0 + 64);

        const __bf16* As = As_[buf];
        const __bf16* Bs = Bs_[buf];
        __builtin_amdgcn_s_setprio(1);
#pragma unroll
        for (int kk = 0; kk < 2; ++kk) {
            bf16x8 af[4], bfr[2];
#pragma unroll
            for (int mi = 0; mi < 4; ++mi) {
                const int row = wr * 64 + mi * 16 + lr;
                af[mi] = *(const bf16x8*)(As + row * 64 + (((kk * 4 + lg) ^ (row & 7)) << 3));
            }
#pragma unroll
            for (int ni = 0; ni < 2; ++ni) {
                const int row = wc * 32 + ni * 16 + lr;
                bfr[ni] = *(const bf16x8*)(Bs + row * 64 + (((kk * 4 + lg) ^ (row & 7)) << 3));
            }
#pragma unroll
            for (int mi = 0; mi < 4; ++mi)
#pragma unroll
                for (int ni = 0; ni < 2; ++ni)
                    acc[mi][ni] = MFMA16(af[mi], bfr[ni], acc[mi][ni]);
        }
        __builtin_amdgcn_s_setprio(0);
        __syncthreads();
        buf ^= 1;
    }
#undef GSTA

    float s1[2], s2[2];
#pragma unroll
    for (int ni = 0; ni < 2; ++ni) { s1[ni] = 0.f; s2[ni] = 0.f; }

    const size_t cb = (size_t)b * 1048576;
#pragma unroll
    for (int mi = 0; mi < 4; ++mi)
#pragma unroll
    for (int q = 0; q < 4; ++q) {
        const int m = m0 + wr * 64 + mi * 16 + lg * 4 + q;
        const float bm = bias[m];
#pragma unroll
        for (int ni = 0; ni < 2; ++ni) {
            const int n = n0 + wc * 32 + ni * 16 + lr;
            const size_t off = cb + (size_t)m * N + n;
            const float v = acc[mi][ni][q] + bm + z[off];
            Cout[off] = v;
            s1[ni] += v;
            s2[ni] += v * v;
        }
    }
#pragma unroll
    for (int msk = 16; msk <= 32; msk <<= 1)
#pragma unroll
        for (int ni = 0; ni < 2; ++ni) {
            s1[ni] += __shfl_xor(s1[ni], msk);
            s2[ni] += __shfl_xor(s2[ni], msk);
        }
    if (lg == 0) {
        const int slot = mt * 2 + wr;   // 0..15
#pragma unroll
        for (int ni = 0; ni < 2; ++ni) {
            const int n = n0 + wc * 32 + ni * 16 + lr;
            const size_t idx2 = ((size_t)slot * 4 + b) * 1024 + n;
            lnS[idx2] = s1[ni];
            lnQ[idx2] = s2[ni];
        }
    }
}

// ---------------------------------------------------------------------------
// Attention half — SOFTWARE-PIPELINED sub-tiles (r19-verified): per 64-j
// interval, phase A = all MFMAs both sub-tiles; phase B = both gathers + exp;
// phase C = P0/PV0, P1/PV1. BD slice-carry. K/V 64x64 dbuf; RK 6x32 ring
// (mod-192); fixed-base softmax (m=0); ones-column row-sum MFMA.
// ---------------------------------------------------------------------------
#define STAGE_KV64(dK, dV, jsup) do {                                         \
    _Pragma("unroll")                                                          \
    for (int cc = 0; cc < 2; ++cc) {                                           \
        const int row_ = w * 16 + cc * 8 + (l >> 3);                           \
        const int c16_ = (l & 7) ^ (row_ & 7);                                 \
        gll16(kbase + (size_t)((jsup) * 64 + row_) * 2048 + c16_ * 8,          \
              (dK) + w * 1024 + cc * 512);                                     \
        gll16(vbase + (size_t)row_ * 1024 + (jsup) * 64 + c16_ * 8,            \
              (dV) + w * 1024 + cc * 512);                                     \
    }                                                                          \
} while (0)

#define STAGE_RK6(c) do {                                                      \
    const int slot_ = mod6(c);                                                 \
    const int loc_  = w * 8 + (l >> 3);                                        \
    const int rc_   = (l & 7) ^ (loc_ & 7);                                    \
    gll16(rkb + (size_t)(rbb + (c) * 32 + loc_) * 1024 + rc_ * 8,              \
          ldsRK + slot_ * 2048 + w * 512);                                     \
} while (0)

static __device__ __forceinline__ void attn_half(
    const int it, const int n, const int b,
    const __bf16* __restrict__ whqkT, const __bf16* __restrict__ kbase,
    const __bf16* __restrict__ vbase, const __bf16* __restrict__ rkb,
    const float* __restrict__ rwb, const float* __restrict__ rrb,
    __bf16* __restrict__ avT,
    __bf16* ldsK0, __bf16* ldsK1, __bf16* ldsV0, __bf16* ldsV1,
    __bf16* ldsRK, __bf16* ps)
{
    const int t  = threadIdx.x;
    const int w  = t >> 6;
    const int l  = t & 63;
    const int lr = l & 15;
    const int lg = l >> 4;
    const int i0   = it * 64;
    const int rbb  = 960 - i0;
    const int rt0  = 3 - w;
    const int nsup = it + 1;

    bf16x8 vone;
#pragma unroll
    for (int e = 0; e < 8; ++e) vone[e] = f2bf(1.0f);

    // ---- Q fragments, scale 0.125 folded ----
    bf16x8 qa[2], qb[2];
    {
        const int iq = i0 + w * 16 + lr;
        const __bf16* qp = whqkT + ((size_t)b * 1024 + iq) * 2048 + n * 64;
#pragma unroll
        for (int h = 0; h < 2; ++h) {
            const bf16x8 q8 = *(const bf16x8*)(qp + h * 32 + lg * 8);
#pragma unroll
            for (int e = 0; e < 8; ++e) {
                const float qv = (float)q8[e];
                qa[h][e] = f2bf((qv + rwb[n * 64 + h * 32 + lg * 8 + e]) * 0.125f);
                qb[h][e] = f2bf((qv + rrb[n * 64 + h * 32 + lg * 8 + e]) * 0.125f);
            }
        }
    }

    f32x4 acc_o[4];
#pragma unroll
    for (int i = 0; i < 4; ++i) acc_o[i] = (f32x4){0.f, 0.f, 0.f, 0.f};
    f32x4 acc_l = (f32x4){0.f, 0.f, 0.f, 0.f};

    // prologue: super 0 K/V + RK chunks 0..3 (covers tiles 0,1)
    STAGE_KV64(ldsK0, ldsV0, 0);
#pragma unroll
    for (int c = 0; c < 4; ++c) STAGE_RK6(c);
    __syncthreads();

    // initial carried BD slice: jt=0, a=0 -> ring rows rt0*16 + lr
    f32x4 bda0 = (f32x4){0.f, 0.f, 0.f, 0.f};
    {
        const int rr = rt0 * 16 + lr;
#pragma unroll
        for (int h = 0; h < 2; ++h) {
            const bf16x8 br = *(const bf16x8*)(
                ldsRK + rr * 64 + (((h * 4 + lg) ^ (rr & 7)) << 3));
            bda0 = MFMA16(qb[h], br, bda0);
        }
    }

    int buf = 0;
    for (int js = 0; js < nsup; ++js) {
        __bf16* kcur = buf ? ldsK1 : ldsK0;
        __bf16* vcur = buf ? ldsV1 : ldsV0;

        if (js + 1 < nsup) {     // async prefetch next super
            __bf16* knxt = buf ? ldsK0 : ldsK1;
            __bf16* vnxt = buf ? ldsV0 : ldsV1;
            STAGE_KV64(knxt, vnxt, js + 1);
            STAGE_RK6(2 * js + 4);
            STAGE_RK6(2 * js + 5);
        }

        const int jt0 = 2 * js;
        const int jt1 = 2 * js + 1;
        const int b192_0 = mod6(jt0) * 32;
        const int b192_1 = mod6(jt1) * 32;

        // ======== PHASE A: all MFMAs for both sub-tiles ========
        __builtin_amdgcn_s_setprio(1);
        f32x4 ac0[2], ac1[2];
#pragma unroll
        for (int nt = 0; nt < 2; ++nt) {
            ac0[nt] = (f32x4){0.f, 0.f, 0.f, 0.f};
            ac1[nt] = (f32x4){0.f, 0.f, 0.f, 0.f};
            const int kr0 = nt * 16 + lr;
            const int kr1 = 32 + nt * 16 + lr;
#pragma unroll
            for (int h = 0; h < 2; ++h) {
                const bf16x8 bk0 = *(const bf16x8*)(
                    kcur + kr0 * 64 + (((h * 4 + lg) ^ (kr0 & 7)) << 3));
                ac0[nt] = MFMA16(qa[h], bk0, ac0[nt]);
                const bf16x8 bk1 = *(const bf16x8*)(
                    kcur + kr1 * 64 + (((h * 4 + lg) ^ (kr1 & 7)) << 3));
                ac1[nt] = MFMA16(qa[h], bk1, ac1[nt]);
            }
        }
        // BD fresh slices: s0 -> (b192_0 +1,+2), s1 -> (b192_1 +1,+2)
        f32x4 bda01 = (f32x4){0.f, 0.f, 0.f, 0.f};
        f32x4 bda02 = (f32x4){0.f, 0.f, 0.f, 0.f};
        f32x4 bda11 = (f32x4){0.f, 0.f, 0.f, 0.f};
        f32x4 bda12 = (f32x4){0.f, 0.f, 0.f, 0.f};
        {
            int r01 = b192_0 + (rt0 + 1) * 16 + lr; if (r01 >= 192) r01 -= 192;
            int r02 = b192_0 + (rt0 + 2) * 16 + lr; if (r02 >= 192) r02 -= 192;
            int r11 = b192_1 + (rt0 + 1) * 16 + lr; if (r11 >= 192) r11 -= 192;
            int r12 = b192_1 + (rt0 + 2) * 16 + lr; if (r12 >= 192) r12 -= 192;
#pragma unroll
            for (int h = 0; h < 2; ++h) {
                const bf16x8 b01 = *(const bf16x8*)(
                    ldsRK + r01 * 64 + (((h * 4 + lg) ^ (r01 & 7)) << 3));
                bda01 = MFMA16(qb[h], b01, bda01);
                const bf16x8 b02 = *(const bf16x8*)(
                    ldsRK + r02 * 64 + (((h * 4 + lg) ^ (r02 & 7)) << 3));
                bda02 = MFMA16(qb[h], b02, bda02);
                const bf16x8 b11 = *(const bf16x8*)(
                    ldsRK + r11 * 64 + (((h * 4 + lg) ^ (r11 & 7)) << 3));
                bda11 = MFMA16(qb[h], b11, bda11);
                const bf16x8 b12 = *(const bf16x8*)(
                    ldsRK + r12 * 64 + (((h * 4 + lg) ^ (r12 & 7)) << 3));
                bda12 = MFMA16(qb[h], b12, bda12);
            }
        }
        __builtin_amdgcn_s_setprio(0);

        // ======== PHASE B: both gathers + exp (fixed base m=0) ========
        float pm0[4][2], pm1[4][2];
#pragma unroll
        for (int q = 0; q < 4; ++q) {
            const int shq  = 15 - lg * 4 - q;
            const int srcl = (l & 48) | ((lr + shq) & 15);
            float s0b[3], s1b[3];
            s0b[0] = __shfl(bda0[q],  srcl, 64);
            s0b[1] = __shfl(bda01[q], srcl, 64);
            s0b[2] = __shfl(bda02[q], srcl, 64);
            s1b[0] = s0b[2];
            s1b[1] = __shfl(bda11[q], srcl, 64);
            s1b[2] = __shfl(bda12[q], srcl, 64);
            const bool lo = (lr + shq) < 16;
            const int gi = i0 + w * 16 + lg * 4 + q;
#pragma unroll
            for (int nt = 0; nt < 2; ++nt) {
                const int gj0 = jt0 * 32 + nt * 16 + lr;
                const float sc0 = ac0[nt][q] + (lo ? s0b[nt] : s0b[nt + 1]);
                pm0[q][nt] = ((gj0 <= gi) && (gj0 >= gi - 999)) ? __expf(sc0) : 0.f;
                const int gj1 = jt1 * 32 + nt * 16 + lr;
                const float sc1 = ac1[nt][q] + (lo ? s1b[nt] : s1b[nt + 1]);
                pm1[q][nt] = ((gj1 <= gi) && (gj1 >= gi - 999)) ? __expf(sc1) : 0.f;
            }
        }
        bda0 = bda12;   // carry to next interval

        // ======== PHASE C: P write + PV per sub-tile ========
#pragma unroll
        for (int q = 0; q < 4; ++q) {
            const int row = w * 16 + lg * 4 + q;
            const int rx  = (row >> 2) & 3;
#pragma unroll
            for (int nt = 0; nt < 2; ++nt)
                ps[row * 32 + (((nt * 2 + (lr >> 3)) ^ rx) << 3) + (lr & 7)] =
                    f2bf(pm0[q][nt]);
        }
        __builtin_amdgcn_s_setprio(1);
        {
            const int prow = w * 16 + lr;
            const bf16x8 ap = *(const bf16x8*)(
                ps + prow * 32 + ((lg ^ ((prow >> 2) & 3)) << 3));
            acc_l = MFMA16(ap, vone, acc_l);
#pragma unroll
            for (int ntd = 0; ntd < 4; ++ntd) {
                const int vrow = ntd * 16 + lr;
                const bf16x8 bv = *(const bf16x8*)(
                    vcur + vrow * 64 + (((0 * 4 + lg) ^ (vrow & 7)) << 3));
                acc_o[ntd] = MFMA16(ap, bv, acc_o[ntd]);
            }
        }
        __builtin_amdgcn_s_setprio(0);
#pragma unroll
        for (int q = 0; q < 4; ++q) {
            const int row = w * 16 + lg * 4 + q;
            const int rx  = (row >> 2) & 3;
#pragma unroll
            for (int nt = 0; nt < 2; ++nt)
                ps[row * 32 + (((nt * 2 + (lr >> 3)) ^ rx) << 3) + (lr & 7)] =
                    f2bf(pm1[q][nt]);
        }
        __builtin_amdgcn_s_setprio(1);
        {
            const int prow = w * 16 + lr;
            const bf16x8 ap = *(const bf16x8*)(
                ps + prow * 32 + ((lg ^ ((prow >> 2) & 3)) << 3));
            acc_l = MFMA16(ap, vone, acc_l);
#pragma unroll
            for (int ntd = 0; ntd < 4; ++ntd) {
                const int vrow = ntd * 16 + lr;
                const bf16x8 bv = *(const bf16x8*)(
                    vcur + vrow * 64 + (((1 * 4 + lg) ^ (vrow & 7)) << 3));
                acc_o[ntd] = MFMA16(ap, bv, acc_o[ntd]);
            }
        }
        __builtin_amdgcn_s_setprio(0);

        __syncthreads();   // next super staged; buffers/ring safe to rotate
        buf ^= 1;
    }

    // ---- output: direct stores ----
    float linv[4];
#pragma unroll
    for (int q = 0; q < 4; ++q) linv[q] = 1.f / acc_l[q];
#pragma unroll
    for (int ntd = 0; ntd < 4; ++ntd)
#pragma unroll
        for (int q = 0; q < 4; ++q) {
            const int row = i0 + w * 16 + lg * 4 + q;
            avT[((size_t)b * 1024 + row) * 1024 + n * 64 + ntd * 16 + lr] =
                f2bf(acc_o[ntd][q] * linv[q]);
        }
}

// ---------------------------------------------------------------------------
// MFMA bf16 fused rel-attention — paired i-tiles (it=pair, 15-pair), each as
// super-tiles of 64 j (pipelined 2 sub-tiles per barrier). 512 uniform
// blocks, XCD-pinned. LDS 60KB -> 2 blocks/CU.
// Ring rows r>=1024 are garbage but provably feed only masked (j>i) scores.
// ---------------------------------------------------------------------------
__global__ __launch_bounds__(256)
void attn_mfma_kernel(const __bf16* __restrict__ whqkT, // [b][l][2048] (Q|K)
                      const __bf16* __restrict__ wh_v,  // [b][1024 c][1024 l]
                      const __bf16* __restrict__ rkT,   // [1024 r][1024 c]
                      const float* __restrict__ rwb,    // (16,64)
                      const float* __restrict__ rrb,    // (16,64)
                      __bf16* __restrict__ avT)         // [b][l][1024]
{
    const int bid  = blockIdx.x;
    const int xcd  = bid & 7;
    const int idx  = bid >> 3;           // 0..63
    const int pair = idx & 7;            // 0..7
    const int nbhi = idx >> 3;           // 0..7
    const int nb   = (nbhi << 3) | xcd;  // 8 (n,b) per XCD
    const int n    = nb >> 2;
    const int b    = nb & 3;

    __shared__ __align__(16) __bf16 ldsK0[64 * 64], ldsK1[64 * 64];  // 8KB x2
    __shared__ __align__(16) __bf16 ldsV0[64 * 64], ldsV1[64 * 64];  // 8KB x2
    __shared__ __align__(16) __bf16 ldsRK[192 * 64];                 // 24KB ring
    __shared__ __align__(16) __bf16 ps[64 * 32];                     // 4KB probs

    const __bf16* kbase = whqkT + (size_t)b * 1024 * 2048 + 1024 + n * 64;
    const __bf16* vbase = wh_v + ((size_t)b * 1024 + n * 64) * 1024;
    const __bf16* rkb   = rkT + n * 64;

    attn_half(pair, n, b, whqkT, kbase, vbase, rkb, rwb, rrb, avT,
              ldsK0, ldsK1, ldsV0, ldsV1, ldsRK, ps);
    attn_half(15 - pair, n, b, whqkT, kbase, vbase, rkb, rwb, rrb, avT,
              ldsK0, ldsK1, ldsV0, ldsV1, ldsRK, ps);
}

// ---------------------------------------------------------------------------
// LN normalize pass (stats precomputed by gemm_out): single read+write.
// Grid dim3(64, 4); block = 16 l's x 16 c-chunks of 64.
// ---------------------------------------------------------------------------
__global__ __launch_bounds__(256)
void ln_kernel(float* __restrict__ x, const float* __restrict__ lnS,
               const float* __restrict__ lnQ)
{
    const int b  = blockIdx.y;
    const int li = threadIdx.x & 15;
    const int cp = threadIdx.x >> 4;
    const int l  = blockIdx.x * 16 + li;
    float* xb = x + (size_t)b * D_MODEL * QLEN;

    float a = 0.f, a2 = 0.f;
#pragma unroll
    for (int slot = 0; slot < 16; ++slot) {
        const size_t idx2 = ((size_t)slot * 4 + b) * 1024 + l;
        a  += lnS[idx2];
        a2 += lnQ[idx2];
    }
    const float mu  = a * (1.f / 1024.f);
    const float var = a2 * (1.f / 1024.f) - mu * mu;
    const float rs  = rsqrtf(var + 1e-5f);

    for (int c = cp * 64; c < (cp + 1) * 64; ++c) {
        const size_t idx = (size_t)c * QLEN + l;
        xb[idx] = (xb[idx] - mu) * rs;
    }
}

// ---------------------------------------------------------------------------
extern "C" void kernel_launch(void* const* d_in, const int* in_sizes, int n_in,
                              void* d_out, int out_size, void* d_ws, size_t ws_size,
                              hipStream_t stream)
{
    const float* z     = (const float*)d_in[0];
    const float* pos   = (const float*)d_in[1];
    const float* u     = (const float*)d_in[2];
    const float* qkv_w = (const float*)d_in[3];
    const float* r_w   = (const float*)d_in[4];
    const float* rwb   = (const float*)d_in[5];
    const float* rrb   = (const float*)d_in[6];
    const float* o_w   = (const float*)d_in[7];
    const float* o_b   = (const float*)d_in[8];
    float* out = (float*)d_out;

    char* p = (char*)d_ws;
    __bf16* whqkT = (__bf16*)p;  p += (size_t)4 * 1024 * 2048 * 2;   // 16.8 MB
    __bf16* wh_v  = (__bf16*)p;  p += (size_t)4 * 1024 * 1024 * 2;   //  8.4 MB
    __bf16* rkT   = (__bf16*)p;  p += (size_t)1024 * 1024 * 2;       //  2.1 MB
    __bf16* avT   = (__bf16*)p;  p += (size_t)4 * 1024 * 1024 * 2;   //  8.4 MB (also RK OOB landing zone)
    __bf16* zT    = (__bf16*)p;  p += (size_t)4 * 1024 * 1024 * 2;   //  8.4 MB
    __bf16* posT  = (__bf16*)p;  p += (size_t)1024 * 1024 * 2;       //  2.1 MB
    __bf16* qw_bf = (__bf16*)p;  p += (size_t)3072 * 1024 * 2;       //  6.3 MB
    __bf16* rw_bf = (__bf16*)p;  p += (size_t)1024 * 1024 * 2;       //  2.1 MB
    __bf16* ow_bf = (__bf16*)p;  p += (size_t)1024 * 1024 * 2;       //  2.1 MB
    float*  lnS   = (float*)p;   p += (size_t)16 * 4 * 1024 * 4;     // 256 KB
    float*  lnQ   = (float*)p;                                       // 256 KB

    // prep: weight converts + transposes in ONE launch
    prep_kernel<<<3840, 256, 0, stream>>>(
        qkv_w, r_w, o_w, z, pos, qw_bf, rw_bf, ow_bf, zT, posT);

    // all pre-attention GEMMs in ONE launch (1664 blocks, 128x64 tiles)
    gemm_pre_kernel<<<1664, 256, 0, stream>>>(
        qw_bf, zT, u, whqkT, wh_v, rw_bf, posT, rkT);

    // fused rel-attention -> avT; 512 uniform paired blocks, pipelined supers
    attn_mfma_kernel<<<512, 256, 0, stream>>>(
        whqkT, wh_v, rkT, rwb, rrb, avT);

    // out = o_w @ attn_vec + o_b + z (fp32, 128x64 tiles) + LN partial stats
    gemm_out_kernel<<<512, 256, 0, stream>>>(ow_bf, avT, z, o_b, out, lnS, lnQ);

    // LN normalize (single pass)
    ln_kernel<<<dim3(64, 4), 256, 0, stream>>>(out, lnS, lnQ);
}

// Round 21
// 139.353 us; speedup vs baseline: 1.0196x; 1.0196x over previous
//
#include <hip/hip_runtime.h>
#include <cmath>

#define D_MODEL 1024
#define QLEN    1024
#define NHEAD   16
#define DHEAD   64
#define BSZ     4

typedef __bf16 bf16x8 __attribute__((ext_vector_type(8)));
typedef float  f32x4  __attribute__((ext_vector_type(4)));

static __device__ __forceinline__ __bf16 f2bf(float x) { return (__bf16)x; }

#define MFMA16(a, b, c) __builtin_amdgcn_mfma_f32_16x16x32_bf16((a), (b), (c), 0, 0, 0)

// async global->LDS, 16B per lane. dest = wave-uniform base + lane*16B.
typedef const __attribute__((address_space(1))) void* gp1_t;
typedef __attribute__((address_space(3))) void* lp3_t;
static __device__ __forceinline__ void gll16(const __bf16* g, const __bf16* l)
{
    __builtin_amdgcn_global_load_lds((gp1_t)g, (lp3_t)(__bf16*)l, 16, 0, 0);
}

static __device__ __forceinline__ int mod6(int c)
{
    if (c >= 24) c -= 24;
    if (c >= 12) c -= 12;
    if (c >= 6)  c -= 6;
    return c;
}

// ---------------------------------------------------------------------------
// MERGED prep: weight converts (bid<2560) + z/pos transpose (2560<=bid<3840).
// ---------------------------------------------------------------------------
__global__ __launch_bounds__(256)
void prep_kernel(const float* __restrict__ qkv_w, const float* __restrict__ r_w,
                 const float* __restrict__ o_w, const float* __restrict__ z,
                 const float* __restrict__ pos, __bf16* __restrict__ qw_bf,
                 __bf16* __restrict__ rw_bf, __bf16* __restrict__ ow_bf,
                 __bf16* __restrict__ zT, __bf16* __restrict__ posT)
{
    const int bid = blockIdx.x;
    if (bid < 2560) {
        const int i = bid * 256 + threadIdx.x;
        const float* s; __bf16* d; int j;
        if (i < 393216)      { s = qkv_w; d = qw_bf; j = i; }
        else if (i < 524288) { s = r_w;   d = rw_bf; j = i - 393216; }
        else                 { s = o_w;   d = ow_bf; j = i - 524288; }
        const float4 a = *(const float4*)(s + (size_t)j * 8);
        const float4 b = *(const float4*)(s + (size_t)j * 8 + 4);
        bf16x8 o;
        o[0] = f2bf(a.x); o[1] = f2bf(a.y); o[2] = f2bf(a.z); o[3] = f2bf(a.w);
        o[4] = f2bf(b.x); o[5] = f2bf(b.y); o[6] = f2bf(b.z); o[7] = f2bf(b.w);
        *(bf16x8*)(d + (size_t)j * 8) = o;
        return;
    }
    // transpose path
    const int lo   = bid - 2560;          // 0..1279
    const int slab = lo >> 8;             // 0..4
    const int rem  = lo & 255;
    const int c0   = (rem >> 4) * 64;
    const int l0   = (rem & 15) * 64;
    const float* src = (slab < 4) ? z + (size_t)slab * 1048576 : pos;
    __bf16*      dst = (slab < 4) ? zT + (size_t)slab * 1048576 : posT;

    __shared__ float tile[64][68];
    const int t = threadIdx.x;
    {
        const int c = t >> 4, l4 = (t & 15) * 4;
#pragma unroll
        for (int r = 0; r < 4; ++r) {
            const int cc = c + r * 16;
            const float4 v = *(const float4*)(src + (size_t)(c0 + cc) * 1024 + l0 + l4);
            tile[cc][l4 + 0] = v.x; tile[cc][l4 + 1] = v.y;
            tile[cc][l4 + 2] = v.z; tile[cc][l4 + 3] = v.w;
        }
    }
    __syncthreads();
    {
        const int l = t >> 2, cb = (t & 3) * 16;
#pragma unroll
        for (int h = 0; h < 2; ++h) {
            bf16x8 o;
#pragma unroll
            for (int e = 0; e < 8; ++e) o[e] = f2bf(tile[cb + h * 8 + e][l]);
            *(bf16x8*)(dst + (size_t)(l0 + l) * 1024 + c0 + cb + h * 8) = o;
        }
    }
}

// ---------------------------------------------------------------------------
// MERGED pre-attention GEMM: QKV-T + V + rk in ONE launch (832 blocks),
// 128x128 tiles, 64KB LDS -> 2 blocks/CU. (r19 configuration: lowest FETCH.)
//   bid [0,512):   mode 1  whqkT[l][c] transposed out (+u), M=2048
//   bid [512,768): mode 0  wh_v natural bf16 out (+u), M=1024 (V section)
//   bid [768,832): mode 2  rkT[r][c] transposed out, M=1024, batch 1
// XCD-pinned via local bid & 7.
// ---------------------------------------------------------------------------
__global__ __launch_bounds__(256)
void gemm_pre_kernel(const __bf16* __restrict__ qw, const __bf16* __restrict__ zT,
                     const float* __restrict__ u, __bf16* __restrict__ whqkT,
                     __bf16* __restrict__ wh_v, const __bf16* __restrict__ rw,
                     const __bf16* __restrict__ posT, __bf16* __restrict__ rkT)
{
    const int bid = blockIdx.x;
    int mode, nt, mt, b;
    const __bf16 *A, *Bb;
    if (bid < 512)      { mode = 1; const int lo = bid;       nt = lo & 7; const int ix = lo >> 3; mt = ix & 15; b = ix >> 4;
                          A = qw;                 Bb = zT + (size_t)b * 1048576; }
    else if (bid < 768) { mode = 0; const int lo = bid - 512; nt = lo & 7; const int ix = lo >> 3; mt = ix & 7;  b = ix >> 3;
                          A = qw + (size_t)2048 * 1024; Bb = zT + (size_t)b * 1048576; }
    else                { mode = 2; const int lo = bid - 768; nt = lo & 7; mt = lo >> 3; b = 0;
                          A = rw;                 Bb = posT; }
    const int m0 = mt * 128;
    const int n0 = nt * 128;
    const int K = 1024;

    __shared__ __align__(16) __bf16 smem[4 * 128 * 64];

    const int t  = threadIdx.x;
    const int w  = t >> 6, l = t & 63;
    const int lr = l & 15, lg = l >> 4;
    const int wr = w >> 1, wc = w & 1;

    f32x4 acc[4][4];
#pragma unroll
    for (int mi = 0; mi < 4; ++mi)
#pragma unroll
        for (int ni = 0; ni < 4; ++ni) acc[mi][ni] = (f32x4){0.f, 0.f, 0.f, 0.f};

#define GSTAGE(bufsel, kk0) do {                                               \
    _Pragma("unroll")                                                          \
    for (int cc = 0; cc < 4; ++cc) {                                           \
        const int ch  = w * 4 + cc;                                            \
        const int row = ch * 8 + (l >> 3);                                     \
        const int c16 = (l & 7) ^ (row & 7);                                   \
        gll16(A  + (size_t)(m0 + row) * K + (kk0) + c16 * 8,                   \
              smem + (bufsel) * 8192 + ch * 512);                              \
        gll16(Bb + (size_t)(n0 + row) * K + (kk0) + c16 * 8,                   \
              smem + 16384 + (bufsel) * 8192 + ch * 512);                      \
    }                                                                          \
} while (0)

    GSTAGE(0, 0);
    __syncthreads();

    int buf = 0;
    for (int k0 = 0; k0 < K; k0 += 64) {
        if (k0 + 64 < K) GSTAGE(buf ^ 1, k0 + 64);

        const __bf16* As = smem + buf * 8192;
        const __bf16* Bs = smem + 16384 + buf * 8192;
        __builtin_amdgcn_s_setprio(1);
#pragma unroll
        for (int kk = 0; kk < 2; ++kk) {
            bf16x8 af[4], bfr[4];
#pragma unroll
            for (int mi = 0; mi < 4; ++mi) {
                const int row = wr * 64 + mi * 16 + lr;
                af[mi] = *(const bf16x8*)(As + row * 64 + (((kk * 4 + lg) ^ (row & 7)) << 3));
            }
#pragma unroll
            for (int ni = 0; ni < 4; ++ni) {
                const int row = wc * 64 + ni * 16 + lr;
                bfr[ni] = *(const bf16x8*)(Bs + row * 64 + (((kk * 4 + lg) ^ (row & 7)) << 3));
            }
#pragma unroll
            for (int mi = 0; mi < 4; ++mi)
#pragma unroll
                for (int ni = 0; ni < 4; ++ni)
                    acc[mi][ni] = MFMA16(af[mi], bfr[ni], acc[mi][ni]);
        }
        __builtin_amdgcn_s_setprio(0);
        __syncthreads();
        buf ^= 1;
    }
#undef GSTAGE

    if (mode == 0) {
        __bf16* Cb = wh_v + (size_t)b * 1048576;
#pragma unroll
        for (int mi = 0; mi < 4; ++mi)
#pragma unroll
        for (int q = 0; q < 4; ++q) {
            const int m = m0 + wr * 64 + mi * 16 + lg * 4 + q;
            const float* up = u + (size_t)b * 3145728 + (size_t)(2048 + m) * 1024;
#pragma unroll
            for (int ni = 0; ni < 4; ++ni) {
                const int n = n0 + wc * 64 + ni * 16 + lr;
                Cb[(size_t)m * 1024 + n] = f2bf(acc[mi][ni][q] + up[n]);
            }
        }
    } else {
        __bf16 (*T)[136] = (__bf16(*)[136])smem;
#pragma unroll
        for (int mi = 0; mi < 4; ++mi)
#pragma unroll
        for (int ni = 0; ni < 4; ++ni)
#pragma unroll
        for (int q = 0; q < 4; ++q) {
            float v = acc[mi][ni][q];
            if (mode == 1) {
                const int m = m0 + wr * 64 + mi * 16 + lg * 4 + q;
                const int n = n0 + wc * 64 + ni * 16 + lr;
                v += u[(size_t)b * 3145728 + (size_t)m * 1024 + n];
            }
            T[wc * 64 + ni * 16 + lr][wr * 64 + mi * 16 + lg * 4 + q] = f2bf(v);
        }
        __syncthreads();
        const int Cw = (mode == 1) ? 2048 : 1024;
        __bf16* co = (mode == 1) ? whqkT + (size_t)b * 1024 * 2048 : rkT;
#pragma unroll
        for (int it2 = 0; it2 < 8; ++it2) {
            const int row = it2 * 16 + w * 4 + (l >> 4);
            const int col = (l & 15) * 8;
            *(bf16x8*)(co + (size_t)(n0 + row) * Cw + m0 + col) = *(const bf16x8*)&T[row][col];
        }
    }
}

// ---------------------------------------------------------------------------
// Out-projection GEMM: 128x64 tiles, 512 blocks, fp32 out, +o_b +z.
// Emits deterministic LN partial stats (slot mt*2+wr of 16).
// ---------------------------------------------------------------------------
__global__ __launch_bounds__(256)
void gemm_out_kernel(const __bf16* __restrict__ A, const __bf16* __restrict__ Bm,
                     const float* __restrict__ z, const float* __restrict__ bias,
                     float* __restrict__ Cout, float* __restrict__ lnS,
                     float* __restrict__ lnQ)
{
    const int nt2 = blockIdx.x & 15;       // 16 n-tiles of 64
    const int idx = blockIdx.x >> 4;
    const int mt  = idx & 7;
    const int b   = idx >> 3;
    const int m0  = mt * 128;
    const int n0  = nt2 * 64;
    const int K = 1024, N = 1024;
    const __bf16* Bb = Bm + (size_t)b * 1048576;

    __shared__ __align__(16) __bf16 As_[2][128 * 64];   // 16KB x2
    __shared__ __align__(16) __bf16 Bs_[2][64 * 64];    // 8KB x2

    const int t  = threadIdx.x;
    const int w  = t >> 6, l = t & 63;
    const int lr = l & 15, lg = l >> 4;
    const int wr = w >> 1, wc = w & 1;

    f32x4 acc[4][2];
#pragma unroll
    for (int mi = 0; mi < 4; ++mi)
#pragma unroll
        for (int ni = 0; ni < 2; ++ni) acc[mi][ni] = (f32x4){0.f, 0.f, 0.f, 0.f};

#define GSTA(bufsel, kk0) do {                                                 \
    _Pragma("unroll")                                                          \
    for (int cc = 0; cc < 4; ++cc) {                                           \
        const int ch  = w * 4 + cc;                                            \
        const int row = ch * 8 + (l >> 3);                                     \
        const int c16 = (l & 7) ^ (row & 7);                                   \
        gll16(A + (size_t)(m0 + row) * K + (kk0) + c16 * 8,                    \
              As_[bufsel] + ch * 512);                                         \
    }                                                                          \
    _Pragma("unroll")                                                          \
    for (int cc = 0; cc < 2; ++cc) {                                           \
        const int ch  = w * 2 + cc;                                            \
        const int row = ch * 8 + (l >> 3);                                     \
        const int c16 = (l & 7) ^ (row & 7);                                   \
        gll16(Bb + (size_t)(n0 + row) * K + (kk0) + c16 * 8,                   \
              Bs_[bufsel] + ch * 512);                                         \
    }                                                                          \
} while (0)

    GSTA(0, 0);
    __syncthreads();

    int buf = 0;
    for (int k0 = 0; k0 < K; k0 += 64) {
        if (k0 + 64 < K) GSTA(buf ^ 1, k0 + 64);

        const __bf16* As = As_[buf];
        const __bf16* Bs = Bs_[buf];
        __builtin_amdgcn_s_setprio(1);
#pragma unroll
        for (int kk = 0; kk < 2; ++kk) {
            bf16x8 af[4], bfr[2];
#pragma unroll
            for (int mi = 0; mi < 4; ++mi) {
                const int row = wr * 64 + mi * 16 + lr;
                af[mi] = *(const bf16x8*)(As + row * 64 + (((kk * 4 + lg) ^ (row & 7)) << 3));
            }
#pragma unroll
            for (int ni = 0; ni < 2; ++ni) {
                const int row = wc * 32 + ni * 16 + lr;
                bfr[ni] = *(const bf16x8*)(Bs + row * 64 + (((kk * 4 + lg) ^ (row & 7)) << 3));
            }
#pragma unroll
            for (int mi = 0; mi < 4; ++mi)
#pragma unroll
                for (int ni = 0; ni < 2; ++ni)
                    acc[mi][ni] = MFMA16(af[mi], bfr[ni], acc[mi][ni]);
        }
        __builtin_amdgcn_s_setprio(0);
        __syncthreads();
        buf ^= 1;
    }
#undef GSTA

    float s1[2], s2[2];
#pragma unroll
    for (int ni = 0; ni < 2; ++ni) { s1[ni] = 0.f; s2[ni] = 0.f; }

    const size_t cb = (size_t)b * 1048576;
#pragma unroll
    for (int mi = 0; mi < 4; ++mi)
#pragma unroll
    for (int q = 0; q < 4; ++q) {
        const int m = m0 + wr * 64 + mi * 16 + lg * 4 + q;
        const float bm = bias[m];
#pragma unroll
        for (int ni = 0; ni < 2; ++ni) {
            const int n = n0 + wc * 32 + ni * 16 + lr;
            const size_t off = cb + (size_t)m * N + n;
            const float v = acc[mi][ni][q] + bm + z[off];
            Cout[off] = v;
            s1[ni] += v;
            s2[ni] += v * v;
        }
    }
#pragma unroll
    for (int msk = 16; msk <= 32; msk <<= 1)
#pragma unroll
        for (int ni = 0; ni < 2; ++ni) {
            s1[ni] += __shfl_xor(s1[ni], msk);
            s2[ni] += __shfl_xor(s2[ni], msk);
        }
    if (lg == 0) {
        const int slot = mt * 2 + wr;   // 0..15
#pragma unroll
        for (int ni = 0; ni < 2; ++ni) {
            const int n = n0 + wc * 32 + ni * 16 + lr;
            const size_t idx2 = ((size_t)slot * 4 + b) * 1024 + n;
            lnS[idx2] = s1[ni];
            lnQ[idx2] = s2[ni];
        }
    }
}

// ---------------------------------------------------------------------------
// Attention half — SOFTWARE-PIPELINED sub-tiles (r19-verified): per 64-j
// interval, phase A = all MFMAs both sub-tiles; phase B = both gathers + exp;
// phase C = P0/PV0, P1/PV1. BD slice-carry. K/V 64x64 dbuf; RK 6x32 ring
// (mod-192); fixed-base softmax (m=0); ones-column row-sum MFMA.
// ---------------------------------------------------------------------------
#define STAGE_KV64(dK, dV, jsup) do {                                         \
    _Pragma("unroll")                                                          \
    for (int cc = 0; cc < 2; ++cc) {                                           \
        const int row_ = w * 16 + cc * 8 + (l >> 3);                           \
        const int c16_ = (l & 7) ^ (row_ & 7);                                 \
        gll16(kbase + (size_t)((jsup) * 64 + row_) * 2048 + c16_ * 8,          \
              (dK) + w * 1024 + cc * 512);                                     \
        gll16(vbase + (size_t)row_ * 1024 + (jsup) * 64 + c16_ * 8,            \
              (dV) + w * 1024 + cc * 512);                                     \
    }                                                                          \
} while (0)

#define STAGE_RK6(c) do {                                                      \
    const int slot_ = mod6(c);                                                 \
    const int loc_  = w * 8 + (l >> 3);                                        \
    const int rc_   = (l & 7) ^ (loc_ & 7);                                    \
    gll16(rkb + (size_t)(rbb + (c) * 32 + loc_) * 1024 + rc_ * 8,              \
          ldsRK + slot_ * 2048 + w * 512);                                     \
} while (0)

static __device__ __forceinline__ void attn_half(
    const int it, const int n, const int b,
    const __bf16* __restrict__ whqkT, const __bf16* __restrict__ kbase,
    const __bf16* __restrict__ vbase, const __bf16* __restrict__ rkb,
    const float* __restrict__ rwb, const float* __restrict__ rrb,
    __bf16* __restrict__ avT,
    __bf16* ldsK0, __bf16* ldsK1, __bf16* ldsV0, __bf16* ldsV1,
    __bf16* ldsRK, __bf16* ps)
{
    const int t  = threadIdx.x;
    const int w  = t >> 6;
    const int l  = t & 63;
    const int lr = l & 15;
    const int lg = l >> 4;
    const int i0   = it * 64;
    const int rbb  = 960 - i0;
    const int rt0  = 3 - w;
    const int nsup = it + 1;

    bf16x8 vone;
#pragma unroll
    for (int e = 0; e < 8; ++e) vone[e] = f2bf(1.0f);

    // ---- Q fragments, scale 0.125 folded ----
    bf16x8 qa[2], qb[2];
    {
        const int iq = i0 + w * 16 + lr;
        const __bf16* qp = whqkT + ((size_t)b * 1024 + iq) * 2048 + n * 64;
#pragma unroll
        for (int h = 0; h < 2; ++h) {
            const bf16x8 q8 = *(const bf16x8*)(qp + h * 32 + lg * 8);
#pragma unroll
            for (int e = 0; e < 8; ++e) {
                const float qv = (float)q8[e];
                qa[h][e] = f2bf((qv + rwb[n * 64 + h * 32 + lg * 8 + e]) * 0.125f);
                qb[h][e] = f2bf((qv + rrb[n * 64 + h * 32 + lg * 8 + e]) * 0.125f);
            }
        }
    }

    f32x4 acc_o[4];
#pragma unroll
    for (int i = 0; i < 4; ++i) acc_o[i] = (f32x4){0.f, 0.f, 0.f, 0.f};
    f32x4 acc_l = (f32x4){0.f, 0.f, 0.f, 0.f};

    // prologue: super 0 K/V + RK chunks 0..3 (covers tiles 0,1)
    STAGE_KV64(ldsK0, ldsV0, 0);
#pragma unroll
    for (int c = 0; c < 4; ++c) STAGE_RK6(c);
    __syncthreads();

    // initial carried BD slice: jt=0, a=0 -> ring rows rt0*16 + lr
    f32x4 bda0 = (f32x4){0.f, 0.f, 0.f, 0.f};
    {
        const int rr = rt0 * 16 + lr;
#pragma unroll
        for (int h = 0; h < 2; ++h) {
            const bf16x8 br = *(const bf16x8*)(
                ldsRK + rr * 64 + (((h * 4 + lg) ^ (rr & 7)) << 3));
            bda0 = MFMA16(qb[h], br, bda0);
        }
    }

    int buf = 0;
    for (int js = 0; js < nsup; ++js) {
        __bf16* kcur = buf ? ldsK1 : ldsK0;
        __bf16* vcur = buf ? ldsV1 : ldsV0;

        if (js + 1 < nsup) {     // async prefetch next super
            __bf16* knxt = buf ? ldsK0 : ldsK1;
            __bf16* vnxt = buf ? ldsV0 : ldsV1;
            STAGE_KV64(knxt, vnxt, js + 1);
            STAGE_RK6(2 * js + 4);
            STAGE_RK6(2 * js + 5);
        }

        const int jt0 = 2 * js;
        const int jt1 = 2 * js + 1;
        const int b192_0 = mod6(jt0) * 32;
        const int b192_1 = mod6(jt1) * 32;

        // ======== PHASE A: all MFMAs for both sub-tiles ========
        __builtin_amdgcn_s_setprio(1);
        f32x4 ac0[2], ac1[2];
#pragma unroll
        for (int nt = 0; nt < 2; ++nt) {
            ac0[nt] = (f32x4){0.f, 0.f, 0.f, 0.f};
            ac1[nt] = (f32x4){0.f, 0.f, 0.f, 0.f};
            const int kr0 = nt * 16 + lr;
            const int kr1 = 32 + nt * 16 + lr;
#pragma unroll
            for (int h = 0; h < 2; ++h) {
                const bf16x8 bk0 = *(const bf16x8*)(
                    kcur + kr0 * 64 + (((h * 4 + lg) ^ (kr0 & 7)) << 3));
                ac0[nt] = MFMA16(qa[h], bk0, ac0[nt]);
                const bf16x8 bk1 = *(const bf16x8*)(
                    kcur + kr1 * 64 + (((h * 4 + lg) ^ (kr1 & 7)) << 3));
                ac1[nt] = MFMA16(qa[h], bk1, ac1[nt]);
            }
        }
        // BD fresh slices: s0 -> (b192_0 +1,+2), s1 -> (b192_1 +1,+2)
        f32x4 bda01 = (f32x4){0.f, 0.f, 0.f, 0.f};
        f32x4 bda02 = (f32x4){0.f, 0.f, 0.f, 0.f};
        f32x4 bda11 = (f32x4){0.f, 0.f, 0.f, 0.f};
        f32x4 bda12 = (f32x4){0.f, 0.f, 0.f, 0.f};
        {
            int r01 = b192_0 + (rt0 + 1) * 16 + lr; if (r01 >= 192) r01 -= 192;
            int r02 = b192_0 + (rt0 + 2) * 16 + lr; if (r02 >= 192) r02 -= 192;
            int r11 = b192_1 + (rt0 + 1) * 16 + lr; if (r11 >= 192) r11 -= 192;
            int r12 = b192_1 + (rt0 + 2) * 16 + lr; if (r12 >= 192) r12 -= 192;
#pragma unroll
            for (int h = 0; h < 2; ++h) {
                const bf16x8 b01 = *(const bf16x8*)(
                    ldsRK + r01 * 64 + (((h * 4 + lg) ^ (r01 & 7)) << 3));
                bda01 = MFMA16(qb[h], b01, bda01);
                const bf16x8 b02 = *(const bf16x8*)(
                    ldsRK + r02 * 64 + (((h * 4 + lg) ^ (r02 & 7)) << 3));
                bda02 = MFMA16(qb[h], b02, bda02);
                const bf16x8 b11 = *(const bf16x8*)(
                    ldsRK + r11 * 64 + (((h * 4 + lg) ^ (r11 & 7)) << 3));
                bda11 = MFMA16(qb[h], b11, bda11);
                const bf16x8 b12 = *(const bf16x8*)(
                    ldsRK + r12 * 64 + (((h * 4 + lg) ^ (r12 & 7)) << 3));
                bda12 = MFMA16(qb[h], b12, bda12);
            }
        }
        __builtin_amdgcn_s_setprio(0);

        // ======== PHASE B: both gathers + exp (fixed base m=0) ========
        float pm0[4][2], pm1[4][2];
#pragma unroll
        for (int q = 0; q < 4; ++q) {
            const int shq  = 15 - lg * 4 - q;
            const int srcl = (l & 48) | ((lr + shq) & 15);
            float s0b[3], s1b[3];
            s0b[0] = __shfl(bda0[q],  srcl, 64);
            s0b[1] = __shfl(bda01[q], srcl, 64);
            s0b[2] = __shfl(bda02[q], srcl, 64);
            s1b[0] = s0b[2];
            s1b[1] = __shfl(bda11[q], srcl, 64);
            s1b[2] = __shfl(bda12[q], srcl, 64);
            const bool lo = (lr + shq) < 16;
            const int gi = i0 + w * 16 + lg * 4 + q;
#pragma unroll
            for (int nt = 0; nt < 2; ++nt) {
                const int gj0 = jt0 * 32 + nt * 16 + lr;
                const float sc0 = ac0[nt][q] + (lo ? s0b[nt] : s0b[nt + 1]);
                pm0[q][nt] = ((gj0 <= gi) && (gj0 >= gi - 999)) ? __expf(sc0) : 0.f;
                const int gj1 = jt1 * 32 + nt * 16 + lr;
                const float sc1 = ac1[nt][q] + (lo ? s1b[nt] : s1b[nt + 1]);
                pm1[q][nt] = ((gj1 <= gi) && (gj1 >= gi - 999)) ? __expf(sc1) : 0.f;
            }
        }
        bda0 = bda12;   // carry to next interval

        // ======== PHASE C: P write + PV per sub-tile ========
#pragma unroll
        for (int q = 0; q < 4; ++q) {
            const int row = w * 16 + lg * 4 + q;
            const int rx  = (row >> 2) & 3;
#pragma unroll
            for (int nt = 0; nt < 2; ++nt)
                ps[row * 32 + (((nt * 2 + (lr >> 3)) ^ rx) << 3) + (lr & 7)] =
                    f2bf(pm0[q][nt]);
        }
        __builtin_amdgcn_s_setprio(1);
        {
            const int prow = w * 16 + lr;
            const bf16x8 ap = *(const bf16x8*)(
                ps + prow * 32 + ((lg ^ ((prow >> 2) & 3)) << 3));
            acc_l = MFMA16(ap, vone, acc_l);
#pragma unroll
            for (int ntd = 0; ntd < 4; ++ntd) {
                const int vrow = ntd * 16 + lr;
                const bf16x8 bv = *(const bf16x8*)(
                    vcur + vrow * 64 + (((0 * 4 + lg) ^ (vrow & 7)) << 3));
                acc_o[ntd] = MFMA16(ap, bv, acc_o[ntd]);
            }
        }
        __builtin_amdgcn_s_setprio(0);
#pragma unroll
        for (int q = 0; q < 4; ++q) {
            const int row = w * 16 + lg * 4 + q;
            const int rx  = (row >> 2) & 3;
#pragma unroll
            for (int nt = 0; nt < 2; ++nt)
                ps[row * 32 + (((nt * 2 + (lr >> 3)) ^ rx) << 3) + (lr & 7)] =
                    f2bf(pm1[q][nt]);
        }
        __builtin_amdgcn_s_setprio(1);
        {
            const int prow = w * 16 + lr;
            const bf16x8 ap = *(const bf16x8*)(
                ps + prow * 32 + ((lg ^ ((prow >> 2) & 3)) << 3));
            acc_l = MFMA16(ap, vone, acc_l);
#pragma unroll
            for (int ntd = 0; ntd < 4; ++ntd) {
                const int vrow = ntd * 16 + lr;
                const bf16x8 bv = *(const bf16x8*)(
                    vcur + vrow * 64 + (((1 * 4 + lg) ^ (vrow & 7)) << 3));
                acc_o[ntd] = MFMA16(ap, bv, acc_o[ntd]);
            }
        }
        __builtin_amdgcn_s_setprio(0);

        __syncthreads();   // next super staged; buffers/ring safe to rotate
        buf ^= 1;
    }

    // ---- output: direct stores ----
    float linv[4];
#pragma unroll
    for (int q = 0; q < 4; ++q) linv[q] = 1.f / acc_l[q];
#pragma unroll
    for (int ntd = 0; ntd < 4; ++ntd)
#pragma unroll
        for (int q = 0; q < 4; ++q) {
            const int row = i0 + w * 16 + lg * 4 + q;
            avT[((size_t)b * 1024 + row) * 1024 + n * 64 + ntd * 16 + lr] =
                f2bf(acc_o[ntd][q] * linv[q]);
        }
}

// ---------------------------------------------------------------------------
// MFMA bf16 fused rel-attention — paired i-tiles (it=pair, 15-pair), each as
// super-tiles of 64 j (pipelined 2 sub-tiles per barrier). 512 uniform
// blocks, XCD-pinned. LDS 60KB -> 2 blocks/CU.
// Ring rows r>=1024 are garbage but provably feed only masked (j>i) scores.
// ---------------------------------------------------------------------------
__global__ __launch_bounds__(256)
void attn_mfma_kernel(const __bf16* __restrict__ whqkT, // [b][l][2048] (Q|K)
                      const __bf16* __restrict__ wh_v,  // [b][1024 c][1024 l]
                      const __bf16* __restrict__ rkT,   // [1024 r][1024 c]
                      const float* __restrict__ rwb,    // (16,64)
                      const float* __restrict__ rrb,    // (16,64)
                      __bf16* __restrict__ avT)         // [b][l][1024]
{
    const int bid  = blockIdx.x;
    const int xcd  = bid & 7;
    const int idx  = bid >> 3;           // 0..63
    const int pair = idx & 7;            // 0..7
    const int nbhi = idx >> 3;           // 0..7
    const int nb   = (nbhi << 3) | xcd;  // 8 (n,b) per XCD
    const int n    = nb >> 2;
    const int b    = nb & 3;

    __shared__ __align__(16) __bf16 ldsK0[64 * 64], ldsK1[64 * 64];  // 8KB x2
    __shared__ __align__(16) __bf16 ldsV0[64 * 64], ldsV1[64 * 64];  // 8KB x2
    __shared__ __align__(16) __bf16 ldsRK[192 * 64];                 // 24KB ring
    __shared__ __align__(16) __bf16 ps[64 * 32];                     // 4KB probs

    const __bf16* kbase = whqkT + (size_t)b * 1024 * 2048 + 1024 + n * 64;
    const __bf16* vbase = wh_v + ((size_t)b * 1024 + n * 64) * 1024;
    const __bf16* rkb   = rkT + n * 64;

    attn_half(pair, n, b, whqkT, kbase, vbase, rkb, rwb, rrb, avT,
              ldsK0, ldsK1, ldsV0, ldsV1, ldsRK, ps);
    attn_half(15 - pair, n, b, whqkT, kbase, vbase, rkb, rwb, rrb, avT,
              ldsK0, ldsK1, ldsV0, ldsV1, ldsRK, ps);
}

// ---------------------------------------------------------------------------
// LN normalize pass (stats precomputed by gemm_out): single read+write.
// Grid dim3(64, 4); block = 16 l's x 16 c-chunks of 64.
// ---------------------------------------------------------------------------
__global__ __launch_bounds__(256)
void ln_kernel(float* __restrict__ x, const float* __restrict__ lnS,
               const float* __restrict__ lnQ)
{
    const int b  = blockIdx.y;
    const int li = threadIdx.x & 15;
    const int cp = threadIdx.x >> 4;
    const int l  = blockIdx.x * 16 + li;
    float* xb = x + (size_t)b * D_MODEL * QLEN;

    float a = 0.f, a2 = 0.f;
#pragma unroll
    for (int slot = 0; slot < 16; ++slot) {
        const size_t idx2 = ((size_t)slot * 4 + b) * 1024 + l;
        a  += lnS[idx2];
        a2 += lnQ[idx2];
    }
    const float mu  = a * (1.f / 1024.f);
    const float var = a2 * (1.f / 1024.f) - mu * mu;
    const float rs  = rsqrtf(var + 1e-5f);

    for (int c = cp * 64; c < (cp + 1) * 64; ++c) {
        const size_t idx = (size_t)c * QLEN + l;
        xb[idx] = (xb[idx] - mu) * rs;
    }
}

// ---------------------------------------------------------------------------
extern "C" void kernel_launch(void* const* d_in, const int* in_sizes, int n_in,
                              void* d_out, int out_size, void* d_ws, size_t ws_size,
                              hipStream_t stream)
{
    const float* z     = (const float*)d_in[0];
    const float* pos   = (const float*)d_in[1];
    const float* u     = (const float*)d_in[2];
    const float* qkv_w = (const float*)d_in[3];
    const float* r_w   = (const float*)d_in[4];
    const float* rwb   = (const float*)d_in[5];
    const float* rrb   = (const float*)d_in[6];
    const float* o_w   = (const float*)d_in[7];
    const float* o_b   = (const float*)d_in[8];
    float* out = (float*)d_out;

    char* p = (char*)d_ws;
    __bf16* whqkT = (__bf16*)p;  p += (size_t)4 * 1024 * 2048 * 2;   // 16.8 MB
    __bf16* wh_v  = (__bf16*)p;  p += (size_t)4 * 1024 * 1024 * 2;   //  8.4 MB
    __bf16* rkT   = (__bf16*)p;  p += (size_t)1024 * 1024 * 2;       //  2.1 MB
    __bf16* avT   = (__bf16*)p;  p += (size_t)4 * 1024 * 1024 * 2;   //  8.4 MB (also RK OOB landing zone)
    __bf16* zT    = (__bf16*)p;  p += (size_t)4 * 1024 * 1024 * 2;   //  8.4 MB
    __bf16* posT  = (__bf16*)p;  p += (size_t)1024 * 1024 * 2;       //  2.1 MB
    __bf16* qw_bf = (__bf16*)p;  p += (size_t)3072 * 1024 * 2;       //  6.3 MB
    __bf16* rw_bf = (__bf16*)p;  p += (size_t)1024 * 1024 * 2;       //  2.1 MB
    __bf16* ow_bf = (__bf16*)p;  p += (size_t)1024 * 1024 * 2;       //  2.1 MB
    float*  lnS   = (float*)p;   p += (size_t)16 * 4 * 1024 * 4;     // 256 KB
    float*  lnQ   = (float*)p;                                       // 256 KB

    // prep: weight converts + transposes in ONE launch
    prep_kernel<<<3840, 256, 0, stream>>>(
        qkv_w, r_w, o_w, z, pos, qw_bf, rw_bf, ow_bf, zT, posT);

    // all pre-attention GEMMs in ONE launch (832 blocks, 128x128 tiles)
    gemm_pre_kernel<<<832, 256, 0, stream>>>(
        qw_bf, zT, u, whqkT, wh_v, rw_bf, posT, rkT);

    // fused rel-attention -> avT; 512 uniform paired blocks, pipelined supers
    attn_mfma_kernel<<<512, 256, 0, stream>>>(
        whqkT, wh_v, rkT, rwb, rrb, avT);

    // out = o_w @ attn_vec + o_b + z (fp32, 128x64 tiles) + LN partial stats
    gemm_out_kernel<<<512, 256, 0, stream>>>(ow_bf, avT, z, o_b, out, lnS, lnQ);

    // LN normalize (single pass)
    ln_kernel<<<dim3(64, 4), 256, 0, stream>>>(out, lnS, lnQ);
}

// Round 22
// 138.620 us; speedup vs baseline: 1.0250x; 1.0053x over previous
//
#include <hip/hip_runtime.h>
#include <cmath>

#define D_MODEL 1024
#define QLEN    1024
#define NHEAD   16
#define DHEAD   64
#define BSZ     4

typedef __bf16 bf16x8 __attribute__((ext_vector_type(8)));
typedef float  f32x4  __attribute__((ext_vector_type(4)));

static __device__ __forceinline__ __bf16 f2bf(float x) { return (__bf16)x; }

#define MFMA16(a, b, c) __builtin_amdgcn_mfma_f32_16x16x32_bf16((a), (b), (c), 0, 0, 0)

// async global->LDS, 16B per lane. dest = wave-uniform base + lane*16B.
typedef const __attribute__((address_space(1))) void* gp1_t;
typedef __attribute__((address_space(3))) void* lp3_t;
static __device__ __forceinline__ void gll16(const __bf16* g, const __bf16* l)
{
    __builtin_amdgcn_global_load_lds((gp1_t)g, (lp3_t)(__bf16*)l, 16, 0, 0);
}

static __device__ __forceinline__ int mod6(int c)
{
    if (c >= 24) c -= 24;
    if (c >= 12) c -= 12;
    if (c >= 6)  c -= 6;
    return c;
}

// ---------------------------------------------------------------------------
// MERGED prep: weight converts (bid<2560) + z/pos transpose (2560<=bid<3840).
// ---------------------------------------------------------------------------
__global__ __launch_bounds__(256)
void prep_kernel(const float* __restrict__ qkv_w, const float* __restrict__ r_w,
                 const float* __restrict__ o_w, const float* __restrict__ z,
                 const float* __restrict__ pos, __bf16* __restrict__ qw_bf,
                 __bf16* __restrict__ rw_bf, __bf16* __restrict__ ow_bf,
                 __bf16* __restrict__ zT, __bf16* __restrict__ posT)
{
    const int bid = blockIdx.x;
    if (bid < 2560) {
        const int i = bid * 256 + threadIdx.x;
        const float* s; __bf16* d; int j;
        if (i < 393216)      { s = qkv_w; d = qw_bf; j = i; }
        else if (i < 524288) { s = r_w;   d = rw_bf; j = i - 393216; }
        else                 { s = o_w;   d = ow_bf; j = i - 524288; }
        const float4 a = *(const float4*)(s + (size_t)j * 8);
        const float4 b = *(const float4*)(s + (size_t)j * 8 + 4);
        bf16x8 o;
        o[0] = f2bf(a.x); o[1] = f2bf(a.y); o[2] = f2bf(a.z); o[3] = f2bf(a.w);
        o[4] = f2bf(b.x); o[5] = f2bf(b.y); o[6] = f2bf(b.z); o[7] = f2bf(b.w);
        *(bf16x8*)(d + (size_t)j * 8) = o;
        return;
    }
    // transpose path
    const int lo   = bid - 2560;          // 0..1279
    const int slab = lo >> 8;             // 0..4
    const int rem  = lo & 255;
    const int c0   = (rem >> 4) * 64;
    const int l0   = (rem & 15) * 64;
    const float* src = (slab < 4) ? z + (size_t)slab * 1048576 : pos;
    __bf16*      dst = (slab < 4) ? zT + (size_t)slab * 1048576 : posT;

    __shared__ float tile[64][68];
    const int t = threadIdx.x;
    {
        const int c = t >> 4, l4 = (t & 15) * 4;
#pragma unroll
        for (int r = 0; r < 4; ++r) {
            const int cc = c + r * 16;
            const float4 v = *(const float4*)(src + (size_t)(c0 + cc) * 1024 + l0 + l4);
            tile[cc][l4 + 0] = v.x; tile[cc][l4 + 1] = v.y;
            tile[cc][l4 + 2] = v.z; tile[cc][l4 + 3] = v.w;
        }
    }
    __syncthreads();
    {
        const int l = t >> 2, cb = (t & 3) * 16;
#pragma unroll
        for (int h = 0; h < 2; ++h) {
            bf16x8 o;
#pragma unroll
            for (int e = 0; e < 8; ++e) o[e] = f2bf(tile[cb + h * 8 + e][l]);
            *(bf16x8*)(dst + (size_t)(l0 + l) * 1024 + c0 + cb + h * 8) = o;
        }
    }
}

// ---------------------------------------------------------------------------
// MERGED pre-attention GEMM: QKV-T + V + rk in ONE launch (832 blocks),
// 128x128 tiles, 64KB LDS -> 2 blocks/CU.  u prefetched into registers at
// k0 == K-128 so the K-loop's drains hide its latency (bit-identical math).
//   bid [0,512):   mode 1  whqkT[l][c] transposed out (+u), M=2048
//   bid [512,768): mode 0  wh_v natural bf16 out (+u), M=1024 (V section)
//   bid [768,832): mode 2  rkT[r][c] transposed out, M=1024, batch 1
// XCD-pinned via local bid & 7.
// ---------------------------------------------------------------------------
__global__ __launch_bounds__(256)
void gemm_pre_kernel(const __bf16* __restrict__ qw, const __bf16* __restrict__ zT,
                     const float* __restrict__ u, __bf16* __restrict__ whqkT,
                     __bf16* __restrict__ wh_v, const __bf16* __restrict__ rw,
                     const __bf16* __restrict__ posT, __bf16* __restrict__ rkT)
{
    const int bid = blockIdx.x;
    int mode, nt, mt, b;
    const __bf16 *A, *Bb;
    if (bid < 512)      { mode = 1; const int lo = bid;       nt = lo & 7; const int ix = lo >> 3; mt = ix & 15; b = ix >> 4;
                          A = qw;                 Bb = zT + (size_t)b * 1048576; }
    else if (bid < 768) { mode = 0; const int lo = bid - 512; nt = lo & 7; const int ix = lo >> 3; mt = ix & 7;  b = ix >> 3;
                          A = qw + (size_t)2048 * 1024; Bb = zT + (size_t)b * 1048576; }
    else                { mode = 2; const int lo = bid - 768; nt = lo & 7; mt = lo >> 3; b = 0;
                          A = rw;                 Bb = posT; }
    const int m0 = mt * 128;
    const int n0 = nt * 128;
    const int K = 1024;

    __shared__ __align__(16) __bf16 smem[4 * 128 * 64];

    const int t  = threadIdx.x;
    const int w  = t >> 6, l = t & 63;
    const int lr = l & 15, lg = l >> 4;
    const int wr = w >> 1, wc = w & 1;

    const float* ubase = (mode == 2) ? nullptr :
        u + (size_t)b * 3145728 + (size_t)((mode == 0 ? 2048 : 0) + m0) * 1024;
    float ur[4][4][4];

    f32x4 acc[4][4];
#pragma unroll
    for (int mi = 0; mi < 4; ++mi)
#pragma unroll
        for (int ni = 0; ni < 4; ++ni) acc[mi][ni] = (f32x4){0.f, 0.f, 0.f, 0.f};

#define GSTAGE(bufsel, kk0) do {                                               \
    _Pragma("unroll")                                                          \
    for (int cc = 0; cc < 4; ++cc) {                                           \
        const int ch  = w * 4 + cc;                                            \
        const int row = ch * 8 + (l >> 3);                                     \
        const int c16 = (l & 7) ^ (row & 7);                                   \
        gll16(A  + (size_t)(m0 + row) * K + (kk0) + c16 * 8,                   \
              smem + (bufsel) * 8192 + ch * 512);                              \
        gll16(Bb + (size_t)(n0 + row) * K + (kk0) + c16 * 8,                   \
              smem + 16384 + (bufsel) * 8192 + ch * 512);                      \
    }                                                                          \
} while (0)

    GSTAGE(0, 0);
    __syncthreads();

    int buf = 0;
    for (int k0 = 0; k0 < K; k0 += 64) {
        if (k0 + 64 < K) GSTAGE(buf ^ 1, k0 + 64);
        if (k0 == K - 128 && mode != 2) {
            // prefetch u for the epilogue (drained by the loop's barriers)
#pragma unroll
            for (int mi = 0; mi < 4; ++mi)
#pragma unroll
            for (int q = 0; q < 4; ++q) {
                const int m = wr * 64 + mi * 16 + lg * 4 + q;
#pragma unroll
                for (int ni = 0; ni < 4; ++ni)
                    ur[mi][q][ni] =
                        ubase[(size_t)m * 1024 + n0 + wc * 64 + ni * 16 + lr];
            }
        }

        const __bf16* As = smem + buf * 8192;
        const __bf16* Bs = smem + 16384 + buf * 8192;
        __builtin_amdgcn_s_setprio(1);
#pragma unroll
        for (int kk = 0; kk < 2; ++kk) {
            bf16x8 af[4], bfr[4];
#pragma unroll
            for (int mi = 0; mi < 4; ++mi) {
                const int row = wr * 64 + mi * 16 + lr;
                af[mi] = *(const bf16x8*)(As + row * 64 + (((kk * 4 + lg) ^ (row & 7)) << 3));
            }
#pragma unroll
            for (int ni = 0; ni < 4; ++ni) {
                const int row = wc * 64 + ni * 16 + lr;
                bfr[ni] = *(const bf16x8*)(Bs + row * 64 + (((kk * 4 + lg) ^ (row & 7)) << 3));
            }
#pragma unroll
            for (int mi = 0; mi < 4; ++mi)
#pragma unroll
                for (int ni = 0; ni < 4; ++ni)
                    acc[mi][ni] = MFMA16(af[mi], bfr[ni], acc[mi][ni]);
        }
        __builtin_amdgcn_s_setprio(0);
        __syncthreads();
        buf ^= 1;
    }
#undef GSTAGE

    if (mode == 0) {
        __bf16* Cb = wh_v + (size_t)b * 1048576;
#pragma unroll
        for (int mi = 0; mi < 4; ++mi)
#pragma unroll
        for (int q = 0; q < 4; ++q) {
            const int m = m0 + wr * 64 + mi * 16 + lg * 4 + q;
#pragma unroll
            for (int ni = 0; ni < 4; ++ni) {
                const int n = n0 + wc * 64 + ni * 16 + lr;
                Cb[(size_t)m * 1024 + n] = f2bf(acc[mi][ni][q] + ur[mi][q][ni]);
            }
        }
    } else {
        __bf16 (*T)[136] = (__bf16(*)[136])smem;
#pragma unroll
        for (int mi = 0; mi < 4; ++mi)
#pragma unroll
        for (int ni = 0; ni < 4; ++ni)
#pragma unroll
        for (int q = 0; q < 4; ++q) {
            float v = acc[mi][ni][q];
            if (mode == 1) v += ur[mi][q][ni];
            T[wc * 64 + ni * 16 + lr][wr * 64 + mi * 16 + lg * 4 + q] = f2bf(v);
        }
        __syncthreads();
        const int Cw = (mode == 1) ? 2048 : 1024;
        __bf16* co = (mode == 1) ? whqkT + (size_t)b * 1024 * 2048 : rkT;
#pragma unroll
        for (int it2 = 0; it2 < 8; ++it2) {
            const int row = it2 * 16 + w * 4 + (l >> 4);
            const int col = (l & 15) * 8;
            *(bf16x8*)(co + (size_t)(n0 + row) * Cw + m0 + col) = *(const bf16x8*)&T[row][col];
        }
    }
}

// ---------------------------------------------------------------------------
// Out-projection GEMM: 128x64 tiles, 512 blocks, fp32 out, +o_b +z.
// z/bias prefetched into registers at k0 == K-128 (latency hidden in-loop).
// Emits deterministic LN partial stats (slot mt*2+wr of 16).
// ---------------------------------------------------------------------------
__global__ __launch_bounds__(256)
void gemm_out_kernel(const __bf16* __restrict__ A, const __bf16* __restrict__ Bm,
                     const float* __restrict__ z, const float* __restrict__ bias,
                     float* __restrict__ Cout, float* __restrict__ lnS,
                     float* __restrict__ lnQ)
{
    const int nt2 = blockIdx.x & 15;       // 16 n-tiles of 64
    const int idx = blockIdx.x >> 4;
    const int mt  = idx & 7;
    const int b   = idx >> 3;
    const int m0  = mt * 128;
    const int n0  = nt2 * 64;
    const int K = 1024, N = 1024;
    const __bf16* Bb = Bm + (size_t)b * 1048576;

    __shared__ __align__(16) __bf16 As_[2][128 * 64];   // 16KB x2
    __shared__ __align__(16) __bf16 Bs_[2][64 * 64];    // 8KB x2

    const int t  = threadIdx.x;
    const int w  = t >> 6, l = t & 63;
    const int lr = l & 15, lg = l >> 4;
    const int wr = w >> 1, wc = w & 1;

    const float* zb = z + (size_t)b * 1048576 + (size_t)m0 * 1024;
    float zr[4][4][2], br_[4][4];

    f32x4 acc[4][2];
#pragma unroll
    for (int mi = 0; mi < 4; ++mi)
#pragma unroll
        for (int ni = 0; ni < 2; ++ni) acc[mi][ni] = (f32x4){0.f, 0.f, 0.f, 0.f};

#define GSTA(bufsel, kk0) do {                                                 \
    _Pragma("unroll")                                                          \
    for (int cc = 0; cc < 4; ++cc) {                                           \
        const int ch  = w * 4 + cc;                                            \
        const int row = ch * 8 + (l >> 3);                                     \
        const int c16 = (l & 7) ^ (row & 7);                                   \
        gll16(A + (size_t)(m0 + row) * K + (kk0) + c16 * 8,                    \
              As_[bufsel] + ch * 512);                                         \
    }                                                                          \
    _Pragma("unroll")                                                          \
    for (int cc = 0; cc < 2; ++cc) {                                           \
        const int ch  = w * 2 + cc;                                            \
        const int row = ch * 8 + (l >> 3);                                     \
        const int c16 = (l & 7) ^ (row & 7);                                   \
        gll16(Bb + (size_t)(n0 + row) * K + (kk0) + c16 * 8,                   \
              Bs_[bufsel] + ch * 512);                                         \
    }                                                                          \
} while (0)

    GSTA(0, 0);
    __syncthreads();

    int buf = 0;
    for (int k0 = 0; k0 < K; k0 += 64) {
        if (k0 + 64 < K) GSTA(buf ^ 1, k0 + 64);
        if (k0 == K - 128) {
#pragma unroll
            for (int mi = 0; mi < 4; ++mi)
#pragma unroll
            for (int q = 0; q < 4; ++q) {
                const int m = wr * 64 + mi * 16 + lg * 4 + q;
                br_[mi][q] = bias[m0 + m];
#pragma unroll
                for (int ni = 0; ni < 2; ++ni)
                    zr[mi][q][ni] =
                        zb[(size_t)m * 1024 + n0 + wc * 32 + ni * 16 + lr];
            }
        }

        const __bf16* As = As_[buf];
        const __bf16* Bs = Bs_[buf];
        __builtin_amdgcn_s_setprio(1);
#pragma unroll
        for (int kk = 0; kk < 2; ++kk) {
            bf16x8 af[4], bfr[2];
#pragma unroll
            for (int mi = 0; mi < 4; ++mi) {
                const int row = wr * 64 + mi * 16 + lr;
                af[mi] = *(const bf16x8*)(As + row * 64 + (((kk * 4 + lg) ^ (row & 7)) << 3));
            }
#pragma unroll
            for (int ni = 0; ni < 2; ++ni) {
                const int row = wc * 32 + ni * 16 + lr;
                bfr[ni] = *(const bf16x8*)(Bs + row * 64 + (((kk * 4 + lg) ^ (row & 7)) << 3));
            }
#pragma unroll
            for (int mi = 0; mi < 4; ++mi)
#pragma unroll
                for (int ni = 0; ni < 2; ++ni)
                    acc[mi][ni] = MFMA16(af[mi], bfr[ni], acc[mi][ni]);
        }
        __builtin_amdgcn_s_setprio(0);
        __syncthreads();
        buf ^= 1;
    }
#undef GSTA

    float s1[2], s2[2];
#pragma unroll
    for (int ni = 0; ni < 2; ++ni) { s1[ni] = 0.f; s2[ni] = 0.f; }

    const size_t cb = (size_t)b * 1048576;
#pragma unroll
    for (int mi = 0; mi < 4; ++mi)
#pragma unroll
    for (int q = 0; q < 4; ++q) {
        const int m = m0 + wr * 64 + mi * 16 + lg * 4 + q;
#pragma unroll
        for (int ni = 0; ni < 2; ++ni) {
            const int n = n0 + wc * 32 + ni * 16 + lr;
            const size_t off = cb + (size_t)m * N + n;
            const float v = acc[mi][ni][q] + br_[mi][q] + zr[mi][q][ni];
            Cout[off] = v;
            s1[ni] += v;
            s2[ni] += v * v;
        }
    }
#pragma unroll
    for (int msk = 16; msk <= 32; msk <<= 1)
#pragma unroll
        for (int ni = 0; ni < 2; ++ni) {
            s1[ni] += __shfl_xor(s1[ni], msk);
            s2[ni] += __shfl_xor(s2[ni], msk);
        }
    if (lg == 0) {
        const int slot = mt * 2 + wr;   // 0..15
#pragma unroll
        for (int ni = 0; ni < 2; ++ni) {
            const int n = n0 + wc * 32 + ni * 16 + lr;
            const size_t idx2 = ((size_t)slot * 4 + b) * 1024 + n;
            lnS[idx2] = s1[ni];
            lnQ[idx2] = s2[ni];
        }
    }
}

// ---------------------------------------------------------------------------
// Attention half — SOFTWARE-PIPELINED sub-tiles (r19-verified): per 64-j
// interval, phase A = all MFMAs both sub-tiles; phase B = both gathers + exp;
// phase C = P0/PV0, P1/PV1. BD slice-carry. K/V 64x64 dbuf; RK 6x32 ring
// (mod-192); fixed-base softmax (m=0); ones-column row-sum MFMA.
// ---------------------------------------------------------------------------
#define STAGE_KV64(dK, dV, jsup) do {                                         \
    _Pragma("unroll")                                                          \
    for (int cc = 0; cc < 2; ++cc) {                                           \
        const int row_ = w * 16 + cc * 8 + (l >> 3);                           \
        const int c16_ = (l & 7) ^ (row_ & 7);                                 \
        gll16(kbase + (size_t)((jsup) * 64 + row_) * 2048 + c16_ * 8,          \
              (dK) + w * 1024 + cc * 512);                                     \
        gll16(vbase + (size_t)row_ * 1024 + (jsup) * 64 + c16_ * 8,            \
              (dV) + w * 1024 + cc * 512);                                     \
    }                                                                          \
} while (0)

#define STAGE_RK6(c) do {                                                      \
    const int slot_ = mod6(c);                                                 \
    const int loc_  = w * 8 + (l >> 3);                                        \
    const int rc_   = (l & 7) ^ (loc_ & 7);                                    \
    gll16(rkb + (size_t)(rbb + (c) * 32 + loc_) * 1024 + rc_ * 8,              \
          ldsRK + slot_ * 2048 + w * 512);                                     \
} while (0)

static __device__ __forceinline__ void attn_half(
    const int it, const int n, const int b,
    const __bf16* __restrict__ whqkT, const __bf16* __restrict__ kbase,
    const __bf16* __restrict__ vbase, const __bf16* __restrict__ rkb,
    const float* __restrict__ rwb, const float* __restrict__ rrb,
    __bf16* __restrict__ avT,
    __bf16* ldsK0, __bf16* ldsK1, __bf16* ldsV0, __bf16* ldsV1,
    __bf16* ldsRK, __bf16* ps)
{
    const int t  = threadIdx.x;
    const int w  = t >> 6;
    const int l  = t & 63;
    const int lr = l & 15;
    const int lg = l >> 4;
    const int i0   = it * 64;
    const int rbb  = 960 - i0;
    const int rt0  = 3 - w;
    const int nsup = it + 1;

    bf16x8 vone;
#pragma unroll
    for (int e = 0; e < 8; ++e) vone[e] = f2bf(1.0f);

    // ---- Q fragments, scale 0.125 folded ----
    bf16x8 qa[2], qb[2];
    {
        const int iq = i0 + w * 16 + lr;
        const __bf16* qp = whqkT + ((size_t)b * 1024 + iq) * 2048 + n * 64;
#pragma unroll
        for (int h = 0; h < 2; ++h) {
            const bf16x8 q8 = *(const bf16x8*)(qp + h * 32 + lg * 8);
#pragma unroll
            for (int e = 0; e < 8; ++e) {
                const float qv = (float)q8[e];
                qa[h][e] = f2bf((qv + rwb[n * 64 + h * 32 + lg * 8 + e]) * 0.125f);
                qb[h][e] = f2bf((qv + rrb[n * 64 + h * 32 + lg * 8 + e]) * 0.125f);
            }
        }
    }

    f32x4 acc_o[4];
#pragma unroll
    for (int i = 0; i < 4; ++i) acc_o[i] = (f32x4){0.f, 0.f, 0.f, 0.f};
    f32x4 acc_l = (f32x4){0.f, 0.f, 0.f, 0.f};

    // prologue: super 0 K/V + RK chunks 0..3 (covers tiles 0,1)
    STAGE_KV64(ldsK0, ldsV0, 0);
#pragma unroll
    for (int c = 0; c < 4; ++c) STAGE_RK6(c);
    __syncthreads();

    // initial carried BD slice: jt=0, a=0 -> ring rows rt0*16 + lr
    f32x4 bda0 = (f32x4){0.f, 0.f, 0.f, 0.f};
    {
        const int rr = rt0 * 16 + lr;
#pragma unroll
        for (int h = 0; h < 2; ++h) {
            const bf16x8 br = *(const bf16x8*)(
                ldsRK + rr * 64 + (((h * 4 + lg) ^ (rr & 7)) << 3));
            bda0 = MFMA16(qb[h], br, bda0);
        }
    }

    int buf = 0;
    for (int js = 0; js < nsup; ++js) {
        __bf16* kcur = buf ? ldsK1 : ldsK0;
        __bf16* vcur = buf ? ldsV1 : ldsV0;

        if (js + 1 < nsup) {     // async prefetch next super
            __bf16* knxt = buf ? ldsK0 : ldsK1;
            __bf16* vnxt = buf ? ldsV0 : ldsV1;
            STAGE_KV64(knxt, vnxt, js + 1);
            STAGE_RK6(2 * js + 4);
            STAGE_RK6(2 * js + 5);
        }

        const int jt0 = 2 * js;
        const int jt1 = 2 * js + 1;
        const int b192_0 = mod6(jt0) * 32;
        const int b192_1 = mod6(jt1) * 32;

        // ======== PHASE A: all MFMAs for both sub-tiles ========
        __builtin_amdgcn_s_setprio(1);
        f32x4 ac0[2], ac1[2];
#pragma unroll
        for (int nt = 0; nt < 2; ++nt) {
            ac0[nt] = (f32x4){0.f, 0.f, 0.f, 0.f};
            ac1[nt] = (f32x4){0.f, 0.f, 0.f, 0.f};
            const int kr0 = nt * 16 + lr;
            const int kr1 = 32 + nt * 16 + lr;
#pragma unroll
            for (int h = 0; h < 2; ++h) {
                const bf16x8 bk0 = *(const bf16x8*)(
                    kcur + kr0 * 64 + (((h * 4 + lg) ^ (kr0 & 7)) << 3));
                ac0[nt] = MFMA16(qa[h], bk0, ac0[nt]);
                const bf16x8 bk1 = *(const bf16x8*)(
                    kcur + kr1 * 64 + (((h * 4 + lg) ^ (kr1 & 7)) << 3));
                ac1[nt] = MFMA16(qa[h], bk1, ac1[nt]);
            }
        }
        // BD fresh slices: s0 -> (b192_0 +1,+2), s1 -> (b192_1 +1,+2)
        f32x4 bda01 = (f32x4){0.f, 0.f, 0.f, 0.f};
        f32x4 bda02 = (f32x4){0.f, 0.f, 0.f, 0.f};
        f32x4 bda11 = (f32x4){0.f, 0.f, 0.f, 0.f};
        f32x4 bda12 = (f32x4){0.f, 0.f, 0.f, 0.f};
        {
            int r01 = b192_0 + (rt0 + 1) * 16 + lr; if (r01 >= 192) r01 -= 192;
            int r02 = b192_0 + (rt0 + 2) * 16 + lr; if (r02 >= 192) r02 -= 192;
            int r11 = b192_1 + (rt0 + 1) * 16 + lr; if (r11 >= 192) r11 -= 192;
            int r12 = b192_1 + (rt0 + 2) * 16 + lr; if (r12 >= 192) r12 -= 192;
#pragma unroll
            for (int h = 0; h < 2; ++h) {
                const bf16x8 b01 = *(const bf16x8*)(
                    ldsRK + r01 * 64 + (((h * 4 + lg) ^ (r01 & 7)) << 3));
                bda01 = MFMA16(qb[h], b01, bda01);
                const bf16x8 b02 = *(const bf16x8*)(
                    ldsRK + r02 * 64 + (((h * 4 + lg) ^ (r02 & 7)) << 3));
                bda02 = MFMA16(qb[h], b02, bda02);
                const bf16x8 b11 = *(const bf16x8*)(
                    ldsRK + r11 * 64 + (((h * 4 + lg) ^ (r11 & 7)) << 3));
                bda11 = MFMA16(qb[h], b11, bda11);
                const bf16x8 b12 = *(const bf16x8*)(
                    ldsRK + r12 * 64 + (((h * 4 + lg) ^ (r12 & 7)) << 3));
                bda12 = MFMA16(qb[h], b12, bda12);
            }
        }
        __builtin_amdgcn_s_setprio(0);

        // ======== PHASE B: both gathers + exp (fixed base m=0) ========
        float pm0[4][2], pm1[4][2];
#pragma unroll
        for (int q = 0; q < 4; ++q) {
            const int shq  = 15 - lg * 4 - q;
            const int srcl = (l & 48) | ((lr + shq) & 15);
            float s0b[3], s1b[3];
            s0b[0] = __shfl(bda0[q],  srcl, 64);
            s0b[1] = __shfl(bda01[q], srcl, 64);
            s0b[2] = __shfl(bda02[q], srcl, 64);
            s1b[0] = s0b[2];
            s1b[1] = __shfl(bda11[q], srcl, 64);
            s1b[2] = __shfl(bda12[q], srcl, 64);
            const bool lo = (lr + shq) < 16;
            const int gi = i0 + w * 16 + lg * 4 + q;
#pragma unroll
            for (int nt = 0; nt < 2; ++nt) {
                const int gj0 = jt0 * 32 + nt * 16 + lr;
                const float sc0 = ac0[nt][q] + (lo ? s0b[nt] : s0b[nt + 1]);
                pm0[q][nt] = ((gj0 <= gi) && (gj0 >= gi - 999)) ? __expf(sc0) : 0.f;
                const int gj1 = jt1 * 32 + nt * 16 + lr;
                const float sc1 = ac1[nt][q] + (lo ? s1b[nt] : s1b[nt + 1]);
                pm1[q][nt] = ((gj1 <= gi) && (gj1 >= gi - 999)) ? __expf(sc1) : 0.f;
            }
        }
        bda0 = bda12;   // carry to next interval

        // ======== PHASE C: P write + PV per sub-tile ========
#pragma unroll
        for (int q = 0; q < 4; ++q) {
            const int row = w * 16 + lg * 4 + q;
            const int rx  = (row >> 2) & 3;
#pragma unroll
            for (int nt = 0; nt < 2; ++nt)
                ps[row * 32 + (((nt * 2 + (lr >> 3)) ^ rx) << 3) + (lr & 7)] =
                    f2bf(pm0[q][nt]);
        }
        __builtin_amdgcn_s_setprio(1);
        {
            const int prow = w * 16 + lr;
            const bf16x8 ap = *(const bf16x8*)(
                ps + prow * 32 + ((lg ^ ((prow >> 2) & 3)) << 3));
            acc_l = MFMA16(ap, vone, acc_l);
#pragma unroll
            for (int ntd = 0; ntd < 4; ++ntd) {
                const int vrow = ntd * 16 + lr;
                const bf16x8 bv = *(const bf16x8*)(
                    vcur + vrow * 64 + (((0 * 4 + lg) ^ (vrow & 7)) << 3));
                acc_o[ntd] = MFMA16(ap, bv, acc_o[ntd]);
            }
        }
        __builtin_amdgcn_s_setprio(0);
#pragma unroll
        for (int q = 0; q < 4; ++q) {
            const int row = w * 16 + lg * 4 + q;
            const int rx  = (row >> 2) & 3;
#pragma unroll
            for (int nt = 0; nt < 2; ++nt)
                ps[row * 32 + (((nt * 2 + (lr >> 3)) ^ rx) << 3) + (lr & 7)] =
                    f2bf(pm1[q][nt]);
        }
        __builtin_amdgcn_s_setprio(1);
        {
            const int prow = w * 16 + lr;
            const bf16x8 ap = *(const bf16x8*)(
                ps + prow * 32 + ((lg ^ ((prow >> 2) & 3)) << 3));
            acc_l = MFMA16(ap, vone, acc_l);
#pragma unroll
            for (int ntd = 0; ntd < 4; ++ntd) {
                const int vrow = ntd * 16 + lr;
                const bf16x8 bv = *(const bf16x8*)(
                    vcur + vrow * 64 + (((1 * 4 + lg) ^ (vrow & 7)) << 3));
                acc_o[ntd] = MFMA16(ap, bv, acc_o[ntd]);
            }
        }
        __builtin_amdgcn_s_setprio(0);

        __syncthreads();   // next super staged; buffers/ring safe to rotate
        buf ^= 1;
    }

    // ---- output: direct stores ----
    float linv[4];
#pragma unroll
    for (int q = 0; q < 4; ++q) linv[q] = 1.f / acc_l[q];
#pragma unroll
    for (int ntd = 0; ntd < 4; ++ntd)
#pragma unroll
        for (int q = 0; q < 4; ++q) {
            const int row = i0 + w * 16 + lg * 4 + q;
            avT[((size_t)b * 1024 + row) * 1024 + n * 64 + ntd * 16 + lr] =
                f2bf(acc_o[ntd][q] * linv[q]);
        }
}

// ---------------------------------------------------------------------------
// MFMA bf16 fused rel-attention — paired i-tiles (it=pair, 15-pair), each as
// super-tiles of 64 j (pipelined 2 sub-tiles per barrier). 512 uniform
// blocks, XCD-pinned. LDS 60KB -> 2 blocks/CU.
// Ring rows r>=1024 are garbage but provably feed only masked (j>i) scores.
// ---------------------------------------------------------------------------
__global__ __launch_bounds__(256)
void attn_mfma_kernel(const __bf16* __restrict__ whqkT, // [b][l][2048] (Q|K)
                      const __bf16* __restrict__ wh_v,  // [b][1024 c][1024 l]
                      const __bf16* __restrict__ rkT,   // [1024 r][1024 c]
                      const float* __restrict__ rwb,    // (16,64)
                      const float* __restrict__ rrb,    // (16,64)
                      __bf16* __restrict__ avT)         // [b][l][1024]
{
    const int bid  = blockIdx.x;
    const int xcd  = bid & 7;
    const int idx  = bid >> 3;           // 0..63
    const int pair = idx & 7;            // 0..7
    const int nbhi = idx >> 3;           // 0..7
    const int nb   = (nbhi << 3) | xcd;  // 8 (n,b) per XCD
    const int n    = nb >> 2;
    const int b    = nb & 3;

    __shared__ __align__(16) __bf16 ldsK0[64 * 64], ldsK1[64 * 64];  // 8KB x2
    __shared__ __align__(16) __bf16 ldsV0[64 * 64], ldsV1[64 * 64];  // 8KB x2
    __shared__ __align__(16) __bf16 ldsRK[192 * 64];                 // 24KB ring
    __shared__ __align__(16) __bf16 ps[64 * 32];                     // 4KB probs

    const __bf16* kbase = whqkT + (size_t)b * 1024 * 2048 + 1024 + n * 64;
    const __bf16* vbase = wh_v + ((size_t)b * 1024 + n * 64) * 1024;
    const __bf16* rkb   = rkT + n * 64;

    attn_half(pair, n, b, whqkT, kbase, vbase, rkb, rwb, rrb, avT,
              ldsK0, ldsK1, ldsV0, ldsV1, ldsRK, ps);
    attn_half(15 - pair, n, b, whqkT, kbase, vbase, rkb, rwb, rrb, avT,
              ldsK0, ldsK1, ldsV0, ldsV1, ldsRK, ps);
}

// ---------------------------------------------------------------------------
// LN normalize pass (stats precomputed by gemm_out): single read+write.
// Grid dim3(64, 4); block = 16 l's x 16 c-chunks of 64.
// ---------------------------------------------------------------------------
__global__ __launch_bounds__(256)
void ln_kernel(float* __restrict__ x, const float* __restrict__ lnS,
               const float* __restrict__ lnQ)
{
    const int b  = blockIdx.y;
    const int li = threadIdx.x & 15;
    const int cp = threadIdx.x >> 4;
    const int l  = blockIdx.x * 16 + li;
    float* xb = x + (size_t)b * D_MODEL * QLEN;

    float a = 0.f, a2 = 0.f;
#pragma unroll
    for (int slot = 0; slot < 16; ++slot) {
        const size_t idx2 = ((size_t)slot * 4 + b) * 1024 + l;
        a  += lnS[idx2];
        a2 += lnQ[idx2];
    }
    const float mu  = a * (1.f / 1024.f);
    const float var = a2 * (1.f / 1024.f) - mu * mu;
    const float rs  = rsqrtf(var + 1e-5f);

    for (int c = cp * 64; c < (cp + 1) * 64; ++c) {
        const size_t idx = (size_t)c * QLEN + l;
        xb[idx] = (xb[idx] - mu) * rs;
    }
}

// ---------------------------------------------------------------------------
extern "C" void kernel_launch(void* const* d_in, const int* in_sizes, int n_in,
                              void* d_out, int out_size, void* d_ws, size_t ws_size,
                              hipStream_t stream)
{
    const float* z     = (const float*)d_in[0];
    const float* pos   = (const float*)d_in[1];
    const float* u     = (const float*)d_in[2];
    const float* qkv_w = (const float*)d_in[3];
    const float* r_w   = (const float*)d_in[4];
    const float* rwb   = (const float*)d_in[5];
    const float* rrb   = (const float*)d_in[6];
    const float* o_w   = (const float*)d_in[7];
    const float* o_b   = (const float*)d_in[8];
    float* out = (float*)d_out;

    char* p = (char*)d_ws;
    __bf16* whqkT = (__bf16*)p;  p += (size_t)4 * 1024 * 2048 * 2;   // 16.8 MB
    __bf16* wh_v  = (__bf16*)p;  p += (size_t)4 * 1024 * 1024 * 2;   //  8.4 MB
    __bf16* rkT   = (__bf16*)p;  p += (size_t)1024 * 1024 * 2;       //  2.1 MB
    __bf16* avT   = (__bf16*)p;  p += (size_t)4 * 1024 * 1024 * 2;   //  8.4 MB (also RK OOB landing zone)
    __bf16* zT    = (__bf16*)p;  p += (size_t)4 * 1024 * 1024 * 2;   //  8.4 MB
    __bf16* posT  = (__bf16*)p;  p += (size_t)1024 * 1024 * 2;       //  2.1 MB
    __bf16* qw_bf = (__bf16*)p;  p += (size_t)3072 * 1024 * 2;       //  6.3 MB
    __bf16* rw_bf = (__bf16*)p;  p += (size_t)1024 * 1024 * 2;       //  2.1 MB
    __bf16* ow_bf = (__bf16*)p;  p += (size_t)1024 * 1024 * 2;       //  2.1 MB
    float*  lnS   = (float*)p;   p += (size_t)16 * 4 * 1024 * 4;     // 256 KB
    float*  lnQ   = (float*)p;                                       // 256 KB

    // prep: weight converts + transposes in ONE launch
    prep_kernel<<<3840, 256, 0, stream>>>(
        qkv_w, r_w, o_w, z, pos, qw_bf, rw_bf, ow_bf, zT, posT);

    // all pre-attention GEMMs in ONE launch (832 blocks, 128x128 tiles)
    gemm_pre_kernel<<<832, 256, 0, stream>>>(
        qw_bf, zT, u, whqkT, wh_v, rw_bf, posT, rkT);

    // fused rel-attention -> avT; 512 uniform paired blocks, pipelined supers
    attn_mfma_kernel<<<512, 256, 0, stream>>>(
        whqkT, wh_v, rkT, rwb, rrb, avT);

    // out = o_w @ attn_vec + o_b + z (fp32, 128x64 tiles) + LN partial stats
    gemm_out_kernel<<<512, 256, 0, stream>>>(ow_bf, avT, z, o_b, out, lnS, lnQ);

    // LN normalize (single pass)
    ln_kernel<<<dim3(64, 4), 256, 0, stream>>>(out, lnS, lnQ);
}